// Round 2
// baseline (1272.447 us; speedup 1.0000x reference)
//
#include <hip/hip_runtime.h>
#include <stdint.h>

#define NN 131072
#define NE 4194304

typedef __bf16 bf16x8 __attribute__((ext_vector_type(8)));
typedef float  floatx4 __attribute__((ext_vector_type(4)));

__device__ __forceinline__ float bf2f(unsigned short u) {
  union { unsigned int i; float f; } v; v.i = ((unsigned int)u) << 16; return v.f;
}
__device__ __forceinline__ unsigned short f2bf(float f) {
  union { float f; unsigned int i; } v; v.f = f;
  unsigned int r = v.i + 0x7fffu + ((v.i >> 16) & 1u);  // RNE
  return (unsigned short)(r >> 16);
}

// ---------------- CSR build ----------------

__global__ __launch_bounds__(256) void k_zero(int* __restrict__ cnt) {
  cnt[blockIdx.x * 256 + threadIdx.x] = 0;
}

__global__ __launch_bounds__(256) void k_count(const int* __restrict__ dst,
                                               int* __restrict__ cnt) {
  const int t = blockIdx.x * 256 + threadIdx.x;
  atomicAdd(&cnt[dst[t]], 1);
}

// single-block exclusive scan over 131072 counts; also dinv = rsqrt(deg+1), cursor=0
__global__ __launch_bounds__(1024) void k_scan(const int* __restrict__ cnt,
                                               int* __restrict__ row_ptr,
                                               float* __restrict__ dinv,
                                               int* __restrict__ cursor) {
  __shared__ int part[1024];
  const int t = threadIdx.x;
  const int CH = NN / 1024;  // 128
  const int base = t * CH;
  int s = 0;
  for (int i = 0; i < CH; ++i) s += cnt[base + i];
  part[t] = s;
  __syncthreads();
  for (int off = 1; off < 1024; off <<= 1) {
    int v = (t >= off) ? part[t - off] : 0;
    __syncthreads();
    part[t] += v;
    __syncthreads();
  }
  int run = (t == 0) ? 0 : part[t - 1];
  for (int i = 0; i < CH; ++i) {
    const int c = cnt[base + i];
    row_ptr[base + i] = run;
    dinv[base + i] = rsqrtf((float)(c + 1));  // +1 self loop, deg>=1 always
    cursor[base + i] = 0;
    run += c;
  }
  if (t == 1023) row_ptr[NN] = run;
}

__global__ __launch_bounds__(256) void k_fill(const int* __restrict__ src,
                                              const int* __restrict__ dst,
                                              const int* __restrict__ row_ptr,
                                              int* __restrict__ cursor,
                                              int* __restrict__ csr) {
  const int t = blockIdx.x * 256 + threadIdx.x;
  const int d = dst[t];
  const int pos = row_ptr[d] + atomicAdd(&cursor[d], 1);
  csr[pos] = src[t];
}

// ---------------- W swizzle (fp32 -> bf16, MFMA B-fragment order) ----------------
// b_frag for (kc,nt): lane q*16+n15 holds B[kc*32+q*8+j][nt*16+n15], j=0..7 contiguous
__global__ __launch_bounds__(256) void k_swizzle(const float* __restrict__ W,
                                                 unsigned short* __restrict__ Wsw) {
  const int t = blockIdx.x * 256 + threadIdx.x;  // t < K*256
  const int k = t >> 8, n = t & 255;
  const int s = ((k >> 5) * 16 + (n >> 4)) * 512 + ((k >> 3) & 3) * 128 + (n & 15) * 8 + (k & 7);
  Wsw[s] = f2bf(W[t]);
}

// ---------------- aggregation (fp32 input): Y = D^-1/2 (A+I) D^-1/2 X ----------------
// F=128, fp32 X, bf16 Y. 32 lanes per row, 2 rows per inner iter.
__global__ __launch_bounds__(256) void agg_f32_128(const float* __restrict__ X,
                                                   const int* __restrict__ row_ptr,
                                                   const int* __restrict__ csr,
                                                   const float* __restrict__ dinv,
                                                   unsigned short* __restrict__ Y) {
  const int lane = threadIdx.x & 63;
  const int node = (blockIdx.x * blockDim.x + threadIdx.x) >> 6;
  const int sub = lane >> 5;        // 0/1
  const int fl = lane & 31;         // feature lane
  const int start = row_ptr[node];
  const int end = row_ptr[node + 1];
  const float di = dinv[node];
  float a0 = 0.f, a1 = 0.f, a2 = 0.f, a3 = 0.f;

  for (int e = start; e < end; e += 64) {
    const int nload = min(end - e, 64);
    int s_l = node;
    float w_l = 0.0f;
    if (lane < nload) { s_l = csr[e + lane]; w_l = dinv[s_l]; }
    for (int j = 0; j < nload; j += 2) {
      const int s = __shfl(s_l, j + sub);
      const float w = __shfl(w_l, j + sub);
      const float4 rv = *(const float4*)(X + (size_t)s * 128 + fl * 4);
      a0 = fmaf(w, rv.x, a0);
      a1 = fmaf(w, rv.y, a1);
      a2 = fmaf(w, rv.z, a2);
      a3 = fmaf(w, rv.w, a3);
    }
  }
  a0 += __shfl_xor(a0, 32);
  a1 += __shfl_xor(a1, 32);
  a2 += __shfl_xor(a2, 32);
  a3 += __shfl_xor(a3, 32);
  const float4 sv = *(const float4*)(X + (size_t)node * 128 + fl * 4);
  a0 = fmaf(di, sv.x, a0);
  a1 = fmaf(di, sv.y, a1);
  a2 = fmaf(di, sv.z, a2);
  a3 = fmaf(di, sv.w, a3);
  if (sub == 0) {
    ushort4 o;
    o.x = f2bf(di * a0);
    o.y = f2bf(di * a1);
    o.z = f2bf(di * a2);
    o.w = f2bf(di * a3);
    *(ushort4*)(Y + (size_t)node * 128 + fl * 4) = o;
  }
}

// F=256, bf16 X, bf16 Y. 64 lanes per row, 1 row per inner iter.
__global__ __launch_bounds__(256) void agg_bf16_256(const unsigned short* __restrict__ X,
                                                    const int* __restrict__ row_ptr,
                                                    const int* __restrict__ csr,
                                                    const float* __restrict__ dinv,
                                                    unsigned short* __restrict__ Y) {
  const int lane = threadIdx.x & 63;
  const int node = (blockIdx.x * blockDim.x + threadIdx.x) >> 6;
  const int start = row_ptr[node];
  const int end = row_ptr[node + 1];
  const float di = dinv[node];
  float a0 = 0.f, a1 = 0.f, a2 = 0.f, a3 = 0.f;

  for (int e = start; e < end; e += 64) {
    const int nload = min(end - e, 64);
    int s_l = node;
    float w_l = 0.0f;
    if (lane < nload) { s_l = csr[e + lane]; w_l = dinv[s_l]; }
    for (int j = 0; j < nload; ++j) {
      const int s = __shfl(s_l, j);
      const float w = __shfl(w_l, j);
      const ushort4 rv = *(const ushort4*)(X + (size_t)s * 256 + lane * 4);
      a0 = fmaf(w, bf2f(rv.x), a0);
      a1 = fmaf(w, bf2f(rv.y), a1);
      a2 = fmaf(w, bf2f(rv.z), a2);
      a3 = fmaf(w, bf2f(rv.w), a3);
    }
  }
  const ushort4 sv = *(const ushort4*)(X + (size_t)node * 256 + lane * 4);
  a0 = fmaf(di, bf2f(sv.x), a0);
  a1 = fmaf(di, bf2f(sv.y), a1);
  a2 = fmaf(di, bf2f(sv.z), a2);
  a3 = fmaf(di, bf2f(sv.w), a3);
  ushort4 o;
  o.x = f2bf(di * a0);
  o.y = f2bf(di * a1);
  o.z = f2bf(di * a2);
  o.w = f2bf(di * a3);
  *(ushort4*)(Y + (size_t)node * 256 + lane * 4) = o;
}

// ---------------- GEMM: out = relu(A[M,K](bf16) @ W[K,256](bf16) + b(fp32)), bf16 out ----------------
// block = 512 thr (8 waves), 256 rows/block (32 rows/wave = 2 m-tiles), all 256 cols
template <int K>  // 128 or 256
__global__ __launch_bounds__(512) void k_gemm(const unsigned short* __restrict__ A,
                                              const unsigned short* __restrict__ Wsw,
                                              const float* __restrict__ bias,
                                              unsigned short* __restrict__ out) {
  __shared__ unsigned short lW[128 * 256];  // 64 KB: one K-half of swizzled W
  const int tid = threadIdx.x;
  const int wave = tid >> 6;
  const int lane = tid & 63;
  const int q = lane >> 4;
  const int m16 = lane & 15;
  const size_t baseM = (size_t)blockIdx.x * 256;

  floatx4 acc[2][16];
#pragma unroll
  for (int t = 0; t < 2; ++t)
#pragma unroll
    for (int nt = 0; nt < 16; ++nt) acc[t][nt] = (floatx4){0.f, 0.f, 0.f, 0.f};

  const size_t rowA0 = baseM + wave * 32 + m16;
  const size_t rowA1 = rowA0 + 16;

  for (int half = 0; half < K / 128; ++half) {
    __syncthreads();  // protect previous half's LDS reads
    const uint4* gsrc = (const uint4*)(Wsw + half * 32768);
    uint4* ldst = (uint4*)lW;
#pragma unroll
    for (int i = 0; i < 8; ++i) ldst[i * 512 + tid] = gsrc[i * 512 + tid];
    __syncthreads();

#pragma unroll
    for (int kc = 0; kc < 4; ++kc) {
      const int koff = half * 128 + kc * 32 + q * 8;
      const bf16x8 av0 = *(const bf16x8*)(A + rowA0 * K + koff);
      const bf16x8 av1 = *(const bf16x8*)(A + rowA1 * K + koff);
#pragma unroll
      for (int nt = 0; nt < 16; ++nt) {
        const bf16x8 bv = *(const bf16x8*)(&lW[(kc * 16 + nt) * 512 + lane * 8]);
        acc[0][nt] = __builtin_amdgcn_mfma_f32_16x16x32_bf16(av0, bv, acc[0][nt], 0, 0, 0);
        acc[1][nt] = __builtin_amdgcn_mfma_f32_16x16x32_bf16(av1, bv, acc[1][nt], 0, 0, 0);
      }
    }
  }
  // epilogue: C/D layout col=lane&15, row=(lane>>4)*4+r  [m89-verified]
  const int rq = (lane >> 4) * 4;
#pragma unroll
  for (int t = 0; t < 2; ++t) {
#pragma unroll
    for (int nt = 0; nt < 16; ++nt) {
      const int col = nt * 16 + m16;
      const float bv = bias[col];
#pragma unroll
      for (int r = 0; r < 4; ++r) {
        const size_t row = baseM + wave * 32 + t * 16 + rq + r;
        float v = acc[t][nt][r] + bv;
        v = fmaxf(v, 0.0f);
        out[row * 256 + col] = f2bf(v);
      }
    }
  }
}

// ---------------- readout: out[g] = sum_{k<4096} Z[g*4096+k]*Wout[k] + bout (fp32 out) ----------------
__global__ __launch_bounds__(256) void k_final(const unsigned short* __restrict__ Z,
                                               const float* __restrict__ Wout,
                                               const float* __restrict__ bout,
                                               float* __restrict__ out) {
  const int lane = threadIdx.x & 63;
  const int g = (blockIdx.x * blockDim.x + threadIdx.x) >> 6;  // 0..8191
  const unsigned short* z = Z + (size_t)g * 4096;
  float acc = 0.f;
#pragma unroll
  for (int it = 0; it < 16; ++it) {
    const int idx = (it * 64 + lane) * 4;
    const ushort4 zv = *(const ushort4*)(z + idx);
    const float4 wv = *(const float4*)(Wout + idx);
    acc = fmaf(bf2f(zv.x), wv.x, acc);
    acc = fmaf(bf2f(zv.y), wv.y, acc);
    acc = fmaf(bf2f(zv.z), wv.z, acc);
    acc = fmaf(bf2f(zv.w), wv.w, acc);
  }
#pragma unroll
  for (int off = 32; off > 0; off >>= 1) acc += __shfl_down(acc, off);
  if (lane == 0) out[g] = acc + bout[0];
}

extern "C" void kernel_launch(void* const* d_in, const int* in_sizes, int n_in,
                              void* d_out, int out_size, void* d_ws, size_t ws_size,
                              hipStream_t stream) {
  const float* x    = (const float*)d_in[0];  // [N,128] fp32
  const int*   ei   = (const int*)d_in[1];    // [2,E] int32
  const float* W1   = (const float*)d_in[2];  // [128,256] fp32
  const float* b1   = (const float*)d_in[3];
  const float* W2   = (const float*)d_in[4];  // [256,256] fp32
  const float* b2   = (const float*)d_in[5];
  const float* Wout = (const float*)d_in[6];  // [4096] fp32
  const float* bout = (const float*)d_in[7];
  float* out = (float*)d_out;

  char* ws = (char*)d_ws;
  size_t off = 0;
  auto alloc = [&](size_t bytes) {
    char* p = ws + off;
    off += (bytes + 511) & ~(size_t)511;
    return p;
  };
  int*            row_ptr = (int*)alloc(((size_t)NN + 1) * 4);
  int*            cnt     = (int*)alloc((size_t)NN * 4);
  int*            cursor  = (int*)alloc((size_t)NN * 4);
  float*          dinv    = (float*)alloc((size_t)NN * 4);
  int*            csr     = (int*)alloc((size_t)NE * 4);
  unsigned short* Wsw1    = (unsigned short*)alloc(128 * 256 * 2);
  unsigned short* Wsw2    = (unsigned short*)alloc(256 * 256 * 2);
  unsigned short* bufA    = (unsigned short*)alloc((size_t)NN * 256 * 2);  // AggX / AggZ1 (bf16)
  unsigned short* bufB    = (unsigned short*)alloc((size_t)NN * 256 * 2);  // Z1 / Z2 (bf16)
  (void)in_sizes; (void)n_in; (void)out_size; (void)ws_size;

  const int* src = ei;
  const int* dst = ei + NE;

  hipLaunchKernelGGL(k_zero,  dim3(NN / 256), dim3(256), 0, stream, cnt);
  hipLaunchKernelGGL(k_count, dim3(NE / 256), dim3(256), 0, stream, dst, cnt);
  hipLaunchKernelGGL(k_scan,  dim3(1), dim3(1024), 0, stream, cnt, row_ptr, dinv, cursor);
  hipLaunchKernelGGL(k_fill,  dim3(NE / 256), dim3(256), 0, stream, src, dst, row_ptr, cursor, csr);
  hipLaunchKernelGGL(k_swizzle, dim3(128), dim3(256), 0, stream, W1, Wsw1);
  hipLaunchKernelGGL(k_swizzle, dim3(256), dim3(256), 0, stream, W2, Wsw2);

  // layer 1: aggregate-then-GEMM (linearity: Agg(X)@W1 == Agg(X@W1))
  hipLaunchKernelGGL(agg_f32_128,  dim3(NN / 4), dim3(256), 0, stream, x, row_ptr, csr, dinv, bufA);
  hipLaunchKernelGGL(k_gemm<128>, dim3(NN / 256), dim3(512), 0, stream, bufA, Wsw1, b1, bufB);
  // layer 2
  hipLaunchKernelGGL(agg_bf16_256, dim3(NN / 4), dim3(256), 0, stream, bufB, row_ptr, csr, dinv, bufA);
  hipLaunchKernelGGL(k_gemm<256>, dim3(NN / 256), dim3(512), 0, stream, bufA, Wsw2, b2, bufB);
  // readout
  hipLaunchKernelGGL(k_final, dim3(8192 / 4), dim3(256), 0, stream, bufB, Wout, bout, out);
}

// Round 3
// 1129.656 us; speedup vs baseline: 1.1264x; 1.1264x over previous
//
#include <hip/hip_runtime.h>
#include <stdint.h>

#define NN 131072
#define NE 4194304

typedef __bf16 bf16x8 __attribute__((ext_vector_type(8)));
typedef float  floatx4 __attribute__((ext_vector_type(4)));
typedef unsigned short u16x8 __attribute__((ext_vector_type(8)));

__device__ __forceinline__ float bf2f(unsigned short u) {
  union { unsigned int i; float f; } v; v.i = ((unsigned int)u) << 16; return v.f;
}
__device__ __forceinline__ unsigned short f2bf(float f) {
  union { float f; unsigned int i; } v; v.f = f;
  unsigned int r = v.i + 0x7fffu + ((v.i >> 16) & 1u);  // RNE
  return (unsigned short)(r >> 16);
}

// ---------------- CSR build ----------------

__global__ __launch_bounds__(256) void k_zero(int* __restrict__ cnt) {
  cnt[blockIdx.x * 256 + threadIdx.x] = 0;
}

__global__ __launch_bounds__(256) void k_count(const int* __restrict__ dst,
                                               int* __restrict__ cnt) {
  const int t = blockIdx.x * 256 + threadIdx.x;
  atomicAdd(&cnt[dst[t]], 1);
}

// single-block exclusive scan over 131072 counts; also dinv = rsqrt(deg+1), cursor=0
__global__ __launch_bounds__(1024) void k_scan(const int* __restrict__ cnt,
                                               int* __restrict__ row_ptr,
                                               float* __restrict__ dinv,
                                               int* __restrict__ cursor) {
  __shared__ int part[1024];
  const int t = threadIdx.x;
  const int CH = NN / 1024;  // 128
  const int base = t * CH;
  int s = 0;
  for (int i = 0; i < CH; ++i) s += cnt[base + i];
  part[t] = s;
  __syncthreads();
  for (int off = 1; off < 1024; off <<= 1) {
    int v = (t >= off) ? part[t - off] : 0;
    __syncthreads();
    part[t] += v;
    __syncthreads();
  }
  int run = (t == 0) ? 0 : part[t - 1];
  for (int i = 0; i < CH; ++i) {
    const int c = cnt[base + i];
    row_ptr[base + i] = run;
    dinv[base + i] = rsqrtf((float)(c + 1));  // +1 self loop
    cursor[base + i] = 0;
    run += c;
  }
  if (t == 1023) row_ptr[NN] = run;
}

// fill CSR with (src, dinv[src]) pairs — removes per-edge dinv gather from both agg layers
__global__ __launch_bounds__(256) void k_fill(const int* __restrict__ src,
                                              const int* __restrict__ dst,
                                              const int* __restrict__ row_ptr,
                                              const float* __restrict__ dinv,
                                              int* __restrict__ cursor,
                                              int2* __restrict__ ew) {
  const int t = blockIdx.x * 256 + threadIdx.x;
  const int d = dst[t];
  const int s = src[t];
  const int pos = row_ptr[d] + atomicAdd(&cursor[d], 1);
  ew[pos] = make_int2(s, __float_as_int(dinv[s]));
}

// ---------------- x fp32 -> bf16 (halves layer-1 gather traffic) ----------------
__global__ __launch_bounds__(256) void k_cvt(const float* __restrict__ X,
                                             unsigned short* __restrict__ Xb) {
  const int t = blockIdx.x * 256 + threadIdx.x;  // NN*128/4 elems
  const float4 v = ((const float4*)X)[t];
  ushort4 o;
  o.x = f2bf(v.x); o.y = f2bf(v.y); o.z = f2bf(v.z); o.w = f2bf(v.w);
  ((ushort4*)Xb)[t] = o;
}

// ---------------- W swizzle (fp32 -> bf16, MFMA B-fragment order) ----------------
__global__ __launch_bounds__(256) void k_swizzle(const float* __restrict__ W,
                                                 unsigned short* __restrict__ Wsw) {
  const int t = blockIdx.x * 256 + threadIdx.x;  // t < K*256
  const int k = t >> 8, n = t & 255;
  const int s = ((k >> 5) * 16 + (n >> 4)) * 512 + ((k >> 3) & 3) * 128 + (n & 15) * 8 + (k & 7);
  Wsw[s] = f2bf(W[t]);
}

// ---------------- aggregation, F=128 (bf16 in/out) ----------------
// 16 lanes per row (16 B/lane), 4 row-groups/wave, unroll 2 -> 8 gathers in flight
__global__ __launch_bounds__(256) void agg_128(const unsigned short* __restrict__ X,
                                               const int* __restrict__ row_ptr,
                                               const int2* __restrict__ ew,
                                               const float* __restrict__ dinv,
                                               unsigned short* __restrict__ Y) {
  const int lane = threadIdx.x & 63;
  const int node = (blockIdx.x * blockDim.x + threadIdx.x) >> 6;
  const int sub = lane >> 4;   // 0..3
  const int fl = lane & 15;    // feature group (8 feats)
  const int start = row_ptr[node];
  const int end = row_ptr[node + 1];
  const float di = dinv[node];
  float a[8] = {0.f, 0.f, 0.f, 0.f, 0.f, 0.f, 0.f, 0.f};
  const unsigned short* Xf = X + fl * 8;

  for (int e = start; e < end; e += 64) {
    const int nload = min(end - e, 64);
    int s_l = node;      // dummy: node row (hot)
    float w_l = 0.0f;
    if (lane < nload) {
      const int2 p = ew[e + lane];
      s_l = p.x;
      w_l = __int_as_float(p.y);
    }
    for (int j = 0; j < nload; j += 8) {
      const int i0 = j + sub, i1 = j + 4 + sub;          // <= 63 always
      const int s0 = __shfl(s_l, i0); const float w0 = __shfl(w_l, i0);
      const int s1 = __shfl(s_l, i1); const float w1 = __shfl(w_l, i1);
      const u16x8 r0 = *(const u16x8*)(Xf + (size_t)s0 * 128);
      const u16x8 r1 = *(const u16x8*)(Xf + (size_t)s1 * 128);
#pragma unroll
      for (int i = 0; i < 8; ++i) a[i] = fmaf(w0, bf2f(r0[i]), a[i]);
#pragma unroll
      for (int i = 0; i < 8; ++i) a[i] = fmaf(w1, bf2f(r1[i]), a[i]);
    }
  }
#pragma unroll
  for (int i = 0; i < 8; ++i) a[i] += __shfl_xor(a[i], 16);
#pragma unroll
  for (int i = 0; i < 8; ++i) a[i] += __shfl_xor(a[i], 32);
  const u16x8 sv = *(const u16x8*)(Xf + (size_t)node * 128);
#pragma unroll
  for (int i = 0; i < 8; ++i) a[i] = fmaf(di, bf2f(sv[i]), a[i]);
  if (sub == 0) {
    u16x8 o;
#pragma unroll
    for (int i = 0; i < 8; ++i) o[i] = f2bf(di * a[i]);
    *(u16x8*)(Y + (size_t)node * 128 + fl * 8) = o;
  }
}

// ---------------- aggregation, F=256 (bf16 in/out) ----------------
// 32 lanes per row (16 B/lane), 2 row-groups/wave, unroll 2 -> 4 gathers in flight
__global__ __launch_bounds__(256) void agg_256(const unsigned short* __restrict__ X,
                                               const int* __restrict__ row_ptr,
                                               const int2* __restrict__ ew,
                                               const float* __restrict__ dinv,
                                               unsigned short* __restrict__ Y) {
  const int lane = threadIdx.x & 63;
  const int node = (blockIdx.x * blockDim.x + threadIdx.x) >> 6;
  const int sub = lane >> 5;   // 0/1
  const int fl = lane & 31;    // feature group (8 feats)
  const int start = row_ptr[node];
  const int end = row_ptr[node + 1];
  const float di = dinv[node];
  float a[8] = {0.f, 0.f, 0.f, 0.f, 0.f, 0.f, 0.f, 0.f};
  const unsigned short* Xf = X + fl * 8;

  for (int e = start; e < end; e += 64) {
    const int nload = min(end - e, 64);
    int s_l = node;
    float w_l = 0.0f;
    if (lane < nload) {
      const int2 p = ew[e + lane];
      s_l = p.x;
      w_l = __int_as_float(p.y);
    }
    for (int j = 0; j < nload; j += 4) {
      const int i0 = j + sub, i1 = j + 2 + sub;          // <= 63 always
      const int s0 = __shfl(s_l, i0); const float w0 = __shfl(w_l, i0);
      const int s1 = __shfl(s_l, i1); const float w1 = __shfl(w_l, i1);
      const u16x8 r0 = *(const u16x8*)(Xf + (size_t)s0 * 256);
      const u16x8 r1 = *(const u16x8*)(Xf + (size_t)s1 * 256);
#pragma unroll
      for (int i = 0; i < 8; ++i) a[i] = fmaf(w0, bf2f(r0[i]), a[i]);
#pragma unroll
      for (int i = 0; i < 8; ++i) a[i] = fmaf(w1, bf2f(r1[i]), a[i]);
    }
  }
#pragma unroll
  for (int i = 0; i < 8; ++i) a[i] += __shfl_xor(a[i], 32);
  const u16x8 sv = *(const u16x8*)(Xf + (size_t)node * 256);
#pragma unroll
  for (int i = 0; i < 8; ++i) a[i] = fmaf(di, bf2f(sv[i]), a[i]);
  if (sub == 0) {
    u16x8 o;
#pragma unroll
    for (int i = 0; i < 8; ++i) o[i] = f2bf(di * a[i]);
    *(u16x8*)(Y + (size_t)node * 256 + fl * 8) = o;
  }
}

// ---------------- GEMM: out = relu(A[M,K](bf16) @ W[K,256](bf16) + b(fp32)), bf16 out ----------------
template <int K>  // 128 or 256
__global__ __launch_bounds__(512) void k_gemm(const unsigned short* __restrict__ A,
                                              const unsigned short* __restrict__ Wsw,
                                              const float* __restrict__ bias,
                                              unsigned short* __restrict__ out) {
  __shared__ unsigned short lW[128 * 256];  // 64 KB: one K-half of swizzled W
  const int tid = threadIdx.x;
  const int wave = tid >> 6;
  const int lane = tid & 63;
  const int q = lane >> 4;
  const int m16 = lane & 15;
  const size_t baseM = (size_t)blockIdx.x * 256;

  floatx4 acc[2][16];
#pragma unroll
  for (int t = 0; t < 2; ++t)
#pragma unroll
    for (int nt = 0; nt < 16; ++nt) acc[t][nt] = (floatx4){0.f, 0.f, 0.f, 0.f};

  const size_t rowA0 = baseM + wave * 32 + m16;
  const size_t rowA1 = rowA0 + 16;

  for (int half = 0; half < K / 128; ++half) {
    __syncthreads();
    const uint4* gsrc = (const uint4*)(Wsw + half * 32768);
    uint4* ldst = (uint4*)lW;
#pragma unroll
    for (int i = 0; i < 8; ++i) ldst[i * 512 + tid] = gsrc[i * 512 + tid];
    __syncthreads();

#pragma unroll
    for (int kc = 0; kc < 4; ++kc) {
      const int koff = half * 128 + kc * 32 + q * 8;
      const bf16x8 av0 = *(const bf16x8*)(A + rowA0 * K + koff);
      const bf16x8 av1 = *(const bf16x8*)(A + rowA1 * K + koff);
#pragma unroll
      for (int nt = 0; nt < 16; ++nt) {
        const bf16x8 bv = *(const bf16x8*)(&lW[(kc * 16 + nt) * 512 + lane * 8]);
        acc[0][nt] = __builtin_amdgcn_mfma_f32_16x16x32_bf16(av0, bv, acc[0][nt], 0, 0, 0);
        acc[1][nt] = __builtin_amdgcn_mfma_f32_16x16x32_bf16(av1, bv, acc[1][nt], 0, 0, 0);
      }
    }
  }
  const int rq = (lane >> 4) * 4;
#pragma unroll
  for (int t = 0; t < 2; ++t) {
#pragma unroll
    for (int nt = 0; nt < 16; ++nt) {
      const int col = nt * 16 + m16;
      const float bv = bias[col];
#pragma unroll
      for (int r = 0; r < 4; ++r) {
        const size_t row = baseM + wave * 32 + t * 16 + rq + r;
        float v = acc[t][nt][r] + bv;
        v = fmaxf(v, 0.0f);
        out[row * 256 + col] = f2bf(v);
      }
    }
  }
}

// ---------------- readout ----------------
__global__ __launch_bounds__(256) void k_final(const unsigned short* __restrict__ Z,
                                               const float* __restrict__ Wout,
                                               const float* __restrict__ bout,
                                               float* __restrict__ out) {
  const int lane = threadIdx.x & 63;
  const int g = (blockIdx.x * blockDim.x + threadIdx.x) >> 6;  // 0..8191
  const unsigned short* z = Z + (size_t)g * 4096;
  float acc = 0.f;
#pragma unroll
  for (int it = 0; it < 16; ++it) {
    const int idx = (it * 64 + lane) * 4;
    const ushort4 zv = *(const ushort4*)(z + idx);
    const float4 wv = *(const float4*)(Wout + idx);
    acc = fmaf(bf2f(zv.x), wv.x, acc);
    acc = fmaf(bf2f(zv.y), wv.y, acc);
    acc = fmaf(bf2f(zv.z), wv.z, acc);
    acc = fmaf(bf2f(zv.w), wv.w, acc);
  }
#pragma unroll
  for (int off = 32; off > 0; off >>= 1) acc += __shfl_down(acc, off);
  if (lane == 0) out[g] = acc + bout[0];
}

extern "C" void kernel_launch(void* const* d_in, const int* in_sizes, int n_in,
                              void* d_out, int out_size, void* d_ws, size_t ws_size,
                              hipStream_t stream) {
  const float* x    = (const float*)d_in[0];  // [N,128] fp32
  const int*   ei   = (const int*)d_in[1];    // [2,E] int32
  const float* W1   = (const float*)d_in[2];  // [128,256] fp32
  const float* b1   = (const float*)d_in[3];
  const float* W2   = (const float*)d_in[4];  // [256,256] fp32
  const float* b2   = (const float*)d_in[5];
  const float* Wout = (const float*)d_in[6];  // [4096] fp32
  const float* bout = (const float*)d_in[7];
  float* out = (float*)d_out;

  char* ws = (char*)d_ws;
  size_t off = 0;
  auto alloc = [&](size_t bytes) {
    char* p = ws + off;
    off += (bytes + 511) & ~(size_t)511;
    return p;
  };
  int*            row_ptr = (int*)alloc(((size_t)NN + 1) * 4);
  int*            cnt     = (int*)alloc((size_t)NN * 4);
  int*            cursor  = (int*)alloc((size_t)NN * 4);
  float*          dinv    = (float*)alloc((size_t)NN * 4);
  int2*           ew      = (int2*)alloc((size_t)NE * 8);
  unsigned short* Wsw1    = (unsigned short*)alloc(128 * 256 * 2);
  unsigned short* Wsw2    = (unsigned short*)alloc(256 * 256 * 2);
  unsigned short* xb      = (unsigned short*)alloc((size_t)NN * 128 * 2);
  unsigned short* bufA    = (unsigned short*)alloc((size_t)NN * 256 * 2);
  unsigned short* bufB    = (unsigned short*)alloc((size_t)NN * 256 * 2);
  (void)in_sizes; (void)n_in; (void)out_size; (void)ws_size;

  const int* src = ei;
  const int* dst = ei + NE;

  hipLaunchKernelGGL(k_zero,  dim3(NN / 256), dim3(256), 0, stream, cnt);
  hipLaunchKernelGGL(k_count, dim3(NE / 256), dim3(256), 0, stream, dst, cnt);
  hipLaunchKernelGGL(k_scan,  dim3(1), dim3(1024), 0, stream, cnt, row_ptr, dinv, cursor);
  hipLaunchKernelGGL(k_fill,  dim3(NE / 256), dim3(256), 0, stream, src, dst, row_ptr, dinv, cursor, ew);
  hipLaunchKernelGGL(k_cvt,   dim3(NN * 128 / 4 / 256), dim3(256), 0, stream, x, xb);
  hipLaunchKernelGGL(k_swizzle, dim3(128), dim3(256), 0, stream, W1, Wsw1);
  hipLaunchKernelGGL(k_swizzle, dim3(256), dim3(256), 0, stream, W2, Wsw2);

  // layer 1: aggregate-then-GEMM (linearity: Agg(X)@W1 == Agg(X@W1))
  hipLaunchKernelGGL(agg_128,  dim3(NN / 4), dim3(256), 0, stream, xb, row_ptr, ew, dinv, bufA);
  hipLaunchKernelGGL(k_gemm<128>, dim3(NN / 256), dim3(512), 0, stream, bufA, Wsw1, b1, bufB);
  // layer 2
  hipLaunchKernelGGL(agg_256,  dim3(NN / 4), dim3(256), 0, stream, bufB, row_ptr, ew, dinv, bufA);
  hipLaunchKernelGGL(k_gemm<256>, dim3(NN / 256), dim3(512), 0, stream, bufA, Wsw2, b2, bufB);
  // readout
  hipLaunchKernelGGL(k_final, dim3(8192 / 4), dim3(256), 0, stream, bufB, Wout, bout, out);
}

// Round 4
// 1092.862 us; speedup vs baseline: 1.1643x; 1.0337x over previous
//
#include <hip/hip_runtime.h>
#include <stdint.h>

#define NN 131072
#define NE 4194304

typedef __bf16 bf16x8 __attribute__((ext_vector_type(8)));
typedef float  floatx4 __attribute__((ext_vector_type(4)));
typedef unsigned short u16x8 __attribute__((ext_vector_type(8)));

__device__ __forceinline__ float bf2f(unsigned short u) {
  union { unsigned int i; float f; } v; v.i = ((unsigned int)u) << 16; return v.f;
}
__device__ __forceinline__ unsigned short f2bf(float f) {
  union { float f; unsigned int i; } v; v.f = f;
  unsigned int r = v.i + 0x7fffu + ((v.i >> 16) & 1u);  // RNE
  return (unsigned short)(r >> 16);
}

// ---------------- CSR build ----------------

__global__ __launch_bounds__(256) void k_zero(int* __restrict__ cnt) {
  cnt[blockIdx.x * 256 + threadIdx.x] = 0;
}

// 4 edges/thread, int4 loads
__global__ __launch_bounds__(256) void k_count(const int* __restrict__ dst,
                                               int* __restrict__ cnt) {
  const int t = blockIdx.x * 256 + threadIdx.x;
  const int4 d = ((const int4*)dst)[t];
  atomicAdd(&cnt[d.x], 1);
  atomicAdd(&cnt[d.y], 1);
  atomicAdd(&cnt[d.z], 1);
  atomicAdd(&cnt[d.w], 1);
}

// block sums: 512 blocks x 256 thr, 1 count/thread
__global__ __launch_bounds__(256) void k_scan1(const int* __restrict__ cnt,
                                               int* __restrict__ partial) {
  __shared__ int red[4];
  const int t = threadIdx.x;
  int v = cnt[blockIdx.x * 256 + t];
#pragma unroll
  for (int off = 32; off > 0; off >>= 1) v += __shfl_down(v, off);
  if ((t & 63) == 0) red[t >> 6] = v;
  __syncthreads();
  if (t == 0) partial[blockIdx.x] = red[0] + red[1] + red[2] + red[3];
}

// exclusive scan of 512 partials, single block
__global__ __launch_bounds__(512) void k_scan2(int* __restrict__ partial) {
  __shared__ int sc[512];
  const int t = threadIdx.x;
  const int c = partial[t];
  sc[t] = c;
  __syncthreads();
  for (int off = 1; off < 512; off <<= 1) {
    int v = (t >= off) ? sc[t - off] : 0;
    __syncthreads();
    sc[t] += v;
    __syncthreads();
  }
  partial[t] = sc[t] - c;  // exclusive
}

// row_ptr + dinv + cursor(=row_ptr) in one pass
__global__ __launch_bounds__(256) void k_scan3(const int* __restrict__ cnt,
                                               const int* __restrict__ partial,
                                               int* __restrict__ row_ptr,
                                               float* __restrict__ dinv,
                                               int* __restrict__ cursor) {
  __shared__ int sc[256];
  const int t = threadIdx.x;
  const int i = blockIdx.x * 256 + t;
  const int c = cnt[i];
  sc[t] = c;
  __syncthreads();
  for (int off = 1; off < 256; off <<= 1) {
    int v = (t >= off) ? sc[t - off] : 0;
    __syncthreads();
    sc[t] += v;
    __syncthreads();
  }
  const int row = partial[blockIdx.x] + sc[t] - c;  // exclusive
  row_ptr[i] = row;
  cursor[i] = row;
  dinv[i] = rsqrtf((float)(c + 1));
  if (i == 0) row_ptr[NN] = NE;
}

// 2 edges/thread; cursor starts at row_ptr -> single random atomic per edge
__global__ __launch_bounds__(256) void k_fill(const int* __restrict__ src,
                                              const int* __restrict__ dst,
                                              int* __restrict__ cursor,
                                              int* __restrict__ csr) {
  const int t = blockIdx.x * 256 + threadIdx.x;
  const int2 s = ((const int2*)src)[t];
  const int2 d = ((const int2*)dst)[t];
  csr[atomicAdd(&cursor[d.x], 1)] = s.x;
  csr[atomicAdd(&cursor[d.y], 1)] = s.y;
}

// ---------------- x fp32 -> bf16 ----------------
__global__ __launch_bounds__(256) void k_cvt(const float* __restrict__ X,
                                             unsigned short* __restrict__ Xb) {
  const int t = blockIdx.x * 256 + threadIdx.x;
  const float4 v = ((const float4*)X)[t];
  ushort4 o;
  o.x = f2bf(v.x); o.y = f2bf(v.y); o.z = f2bf(v.z); o.w = f2bf(v.w);
  ((ushort4*)Xb)[t] = o;
}

// ---------------- W swizzle (fp32 -> bf16, MFMA B-fragment order) ----------------
__global__ __launch_bounds__(256) void k_swizzle(const float* __restrict__ W,
                                                 unsigned short* __restrict__ Wsw) {
  const int t = blockIdx.x * 256 + threadIdx.x;  // t < K*256
  const int k = t >> 8, n = t & 255;
  const int s = ((k >> 5) * 16 + (n >> 4)) * 512 + ((k >> 3) & 3) * 128 + (n & 15) * 8 + (k & 7);
  Wsw[s] = f2bf(W[t]);
}

// ---------------- aggregation, F=128 ----------------
// 16 lanes/row, 4 row-groups/wave, 4 loads in flight (16 edges per j-iter)
__global__ __launch_bounds__(256) void agg_128(const unsigned short* __restrict__ X,
                                               const int* __restrict__ row_ptr,
                                               const int* __restrict__ csr,
                                               const float* __restrict__ dinv,
                                               unsigned short* __restrict__ Y,
                                               int node_base) {
  const int lane = threadIdx.x & 63;
  const int node = node_base + ((blockIdx.x * blockDim.x + threadIdx.x) >> 6);
  const int sub = lane >> 4;   // 0..3
  const int fl = lane & 15;
  const int start = row_ptr[node];
  const int end = row_ptr[node + 1];
  const float di = dinv[node];
  float a[8] = {0.f, 0.f, 0.f, 0.f, 0.f, 0.f, 0.f, 0.f};
  const unsigned short* Xf = X + fl * 8;

  for (int e = start; e < end; e += 64) {
    const int nload = min(end - e, 64);
    int s_l = node;
    float w_l = 0.0f;
    if (lane < nload) { s_l = csr[e + lane]; w_l = dinv[s_l]; }
    for (int j = 0; j < nload; j += 16) {
      const int i0 = j + sub, i1 = j + 4 + sub, i2 = j + 8 + sub, i3 = j + 12 + sub;  // <= 63
      const int s0 = __shfl(s_l, i0); const float w0 = __shfl(w_l, i0);
      const int s1 = __shfl(s_l, i1); const float w1 = __shfl(w_l, i1);
      const int s2 = __shfl(s_l, i2); const float w2 = __shfl(w_l, i2);
      const int s3 = __shfl(s_l, i3); const float w3 = __shfl(w_l, i3);
      const u16x8 r0 = *(const u16x8*)(Xf + (size_t)s0 * 128);
      const u16x8 r1 = *(const u16x8*)(Xf + (size_t)s1 * 128);
      const u16x8 r2 = *(const u16x8*)(Xf + (size_t)s2 * 128);
      const u16x8 r3 = *(const u16x8*)(Xf + (size_t)s3 * 128);
#pragma unroll
      for (int i = 0; i < 8; ++i) a[i] = fmaf(w0, bf2f(r0[i]), a[i]);
#pragma unroll
      for (int i = 0; i < 8; ++i) a[i] = fmaf(w1, bf2f(r1[i]), a[i]);
#pragma unroll
      for (int i = 0; i < 8; ++i) a[i] = fmaf(w2, bf2f(r2[i]), a[i]);
#pragma unroll
      for (int i = 0; i < 8; ++i) a[i] = fmaf(w3, bf2f(r3[i]), a[i]);
    }
  }
#pragma unroll
  for (int i = 0; i < 8; ++i) a[i] += __shfl_xor(a[i], 16);
#pragma unroll
  for (int i = 0; i < 8; ++i) a[i] += __shfl_xor(a[i], 32);
  const u16x8 sv = *(const u16x8*)(Xf + (size_t)node * 128);
#pragma unroll
  for (int i = 0; i < 8; ++i) a[i] = fmaf(di, bf2f(sv[i]), a[i]);
  if (sub == 0) {
    u16x8 o;
#pragma unroll
    for (int i = 0; i < 8; ++i) o[i] = f2bf(di * a[i]);
    *(u16x8*)(Y + (size_t)node * 128 + fl * 8) = o;
  }
}

// ---------------- aggregation, F=256 ----------------
// 32 lanes/row, 2 row-groups/wave, 4 loads in flight (8 edges per j-iter)
__global__ __launch_bounds__(256) void agg_256(const unsigned short* __restrict__ X,
                                               const int* __restrict__ row_ptr,
                                               const int* __restrict__ csr,
                                               const float* __restrict__ dinv,
                                               unsigned short* __restrict__ Y,
                                               int node_base) {
  const int lane = threadIdx.x & 63;
  const int node = node_base + ((blockIdx.x * blockDim.x + threadIdx.x) >> 6);
  const int sub = lane >> 5;   // 0/1
  const int fl = lane & 31;
  const int start = row_ptr[node];
  const int end = row_ptr[node + 1];
  const float di = dinv[node];
  float a[8] = {0.f, 0.f, 0.f, 0.f, 0.f, 0.f, 0.f, 0.f};
  const unsigned short* Xf = X + fl * 8;

  for (int e = start; e < end; e += 64) {
    const int nload = min(end - e, 64);
    int s_l = node;
    float w_l = 0.0f;
    if (lane < nload) { s_l = csr[e + lane]; w_l = dinv[s_l]; }
    for (int j = 0; j < nload; j += 8) {
      const int i0 = j + sub, i1 = j + 2 + sub, i2 = j + 4 + sub, i3 = j + 6 + sub;  // <= 63
      const int s0 = __shfl(s_l, i0); const float w0 = __shfl(w_l, i0);
      const int s1 = __shfl(s_l, i1); const float w1 = __shfl(w_l, i1);
      const int s2 = __shfl(s_l, i2); const float w2 = __shfl(w_l, i2);
      const int s3 = __shfl(s_l, i3); const float w3 = __shfl(w_l, i3);
      const u16x8 r0 = *(const u16x8*)(Xf + (size_t)s0 * 256);
      const u16x8 r1 = *(const u16x8*)(Xf + (size_t)s1 * 256);
      const u16x8 r2 = *(const u16x8*)(Xf + (size_t)s2 * 256);
      const u16x8 r3 = *(const u16x8*)(Xf + (size_t)s3 * 256);
#pragma unroll
      for (int i = 0; i < 8; ++i) a[i] = fmaf(w0, bf2f(r0[i]), a[i]);
#pragma unroll
      for (int i = 0; i < 8; ++i) a[i] = fmaf(w1, bf2f(r1[i]), a[i]);
#pragma unroll
      for (int i = 0; i < 8; ++i) a[i] = fmaf(w2, bf2f(r2[i]), a[i]);
#pragma unroll
      for (int i = 0; i < 8; ++i) a[i] = fmaf(w3, bf2f(r3[i]), a[i]);
    }
  }
#pragma unroll
  for (int i = 0; i < 8; ++i) a[i] += __shfl_xor(a[i], 32);
  const u16x8 sv = *(const u16x8*)(Xf + (size_t)node * 256);
#pragma unroll
  for (int i = 0; i < 8; ++i) a[i] = fmaf(di, bf2f(sv[i]), a[i]);
  if (sub == 0) {
    u16x8 o;
#pragma unroll
    for (int i = 0; i < 8; ++i) o[i] = f2bf(di * a[i]);
    *(u16x8*)(Y + (size_t)node * 256 + fl * 8) = o;
  }
}

// ---------------- GEMM: out = relu(A[M,K](bf16) @ W[K,256](bf16) + b(fp32)), bf16 out ----------------
template <int K>  // 128 or 256
__global__ __launch_bounds__(512) void k_gemm(const unsigned short* __restrict__ A,
                                              const unsigned short* __restrict__ Wsw,
                                              const float* __restrict__ bias,
                                              unsigned short* __restrict__ out) {
  __shared__ unsigned short lW[128 * 256];  // 64 KB: one K-half of swizzled W
  const int tid = threadIdx.x;
  const int wave = tid >> 6;
  const int lane = tid & 63;
  const int q = lane >> 4;
  const int m16 = lane & 15;
  const size_t baseM = (size_t)blockIdx.x * 256;

  floatx4 acc[2][16];
#pragma unroll
  for (int t = 0; t < 2; ++t)
#pragma unroll
    for (int nt = 0; nt < 16; ++nt) acc[t][nt] = (floatx4){0.f, 0.f, 0.f, 0.f};

  const size_t rowA0 = baseM + wave * 32 + m16;
  const size_t rowA1 = rowA0 + 16;

  for (int half = 0; half < K / 128; ++half) {
    __syncthreads();
    const uint4* gsrc = (const uint4*)(Wsw + half * 32768);
    uint4* ldst = (uint4*)lW;
#pragma unroll
    for (int i = 0; i < 8; ++i) ldst[i * 512 + tid] = gsrc[i * 512 + tid];
    __syncthreads();

#pragma unroll
    for (int kc = 0; kc < 4; ++kc) {
      const int koff = half * 128 + kc * 32 + q * 8;
      const bf16x8 av0 = *(const bf16x8*)(A + rowA0 * K + koff);
      const bf16x8 av1 = *(const bf16x8*)(A + rowA1 * K + koff);
#pragma unroll
      for (int nt = 0; nt < 16; ++nt) {
        const bf16x8 bv = *(const bf16x8*)(&lW[(kc * 16 + nt) * 512 + lane * 8]);
        acc[0][nt] = __builtin_amdgcn_mfma_f32_16x16x32_bf16(av0, bv, acc[0][nt], 0, 0, 0);
        acc[1][nt] = __builtin_amdgcn_mfma_f32_16x16x32_bf16(av1, bv, acc[1][nt], 0, 0, 0);
      }
    }
  }
  const int rq = (lane >> 4) * 4;
#pragma unroll
  for (int t = 0; t < 2; ++t) {
#pragma unroll
    for (int nt = 0; nt < 16; ++nt) {
      const int col = nt * 16 + m16;
      const float bv = bias[col];
#pragma unroll
      for (int r = 0; r < 4; ++r) {
        const size_t row = baseM + wave * 32 + t * 16 + rq + r;
        float v = acc[t][nt][r] + bv;
        v = fmaxf(v, 0.0f);
        out[row * 256 + col] = f2bf(v);
      }
    }
  }
}

// ---------------- readout ----------------
__global__ __launch_bounds__(256) void k_final(const unsigned short* __restrict__ Z,
                                               const float* __restrict__ Wout,
                                               const float* __restrict__ bout,
                                               float* __restrict__ out) {
  const int lane = threadIdx.x & 63;
  const int g = (blockIdx.x * blockDim.x + threadIdx.x) >> 6;  // 0..8191
  const unsigned short* z = Z + (size_t)g * 4096;
  float acc = 0.f;
#pragma unroll
  for (int it = 0; it < 16; ++it) {
    const int idx = (it * 64 + lane) * 4;
    const ushort4 zv = *(const ushort4*)(z + idx);
    const float4 wv = *(const float4*)(Wout + idx);
    acc = fmaf(bf2f(zv.x), wv.x, acc);
    acc = fmaf(bf2f(zv.y), wv.y, acc);
    acc = fmaf(bf2f(zv.z), wv.z, acc);
    acc = fmaf(bf2f(zv.w), wv.w, acc);
  }
#pragma unroll
  for (int off = 32; off > 0; off >>= 1) acc += __shfl_down(acc, off);
  if (lane == 0) out[g] = acc + bout[0];
}

extern "C" void kernel_launch(void* const* d_in, const int* in_sizes, int n_in,
                              void* d_out, int out_size, void* d_ws, size_t ws_size,
                              hipStream_t stream) {
  const float* x    = (const float*)d_in[0];  // [N,128] fp32
  const int*   ei   = (const int*)d_in[1];    // [2,E] int32
  const float* W1   = (const float*)d_in[2];  // [128,256] fp32
  const float* b1   = (const float*)d_in[3];
  const float* W2   = (const float*)d_in[4];  // [256,256] fp32
  const float* b2   = (const float*)d_in[5];
  const float* Wout = (const float*)d_in[6];  // [4096] fp32
  const float* bout = (const float*)d_in[7];
  float* out = (float*)d_out;

  char* ws = (char*)d_ws;
  size_t off = 0;
  auto alloc = [&](size_t bytes) {
    char* p = ws + off;
    off += (bytes + 511) & ~(size_t)511;
    return p;
  };
  int*            row_ptr = (int*)alloc(((size_t)NN + 1) * 4);
  int*            cnt     = (int*)alloc((size_t)NN * 4);
  int*            cursor  = (int*)alloc((size_t)NN * 4);
  float*          dinv    = (float*)alloc((size_t)NN * 4);
  int*            partial = (int*)alloc(512 * 4);
  int*            csr     = (int*)alloc((size_t)NE * 4);
  unsigned short* Wsw1    = (unsigned short*)alloc(128 * 256 * 2);
  unsigned short* Wsw2    = (unsigned short*)alloc(256 * 256 * 2);
  unsigned short* xb      = (unsigned short*)alloc((size_t)NN * 128 * 2);
  unsigned short* bufA    = (unsigned short*)alloc((size_t)NN * 256 * 2);
  unsigned short* bufB    = (unsigned short*)alloc((size_t)NN * 256 * 2);
  (void)in_sizes; (void)n_in; (void)out_size; (void)ws_size;

  const int* src = ei;
  const int* dst = ei + NE;

  hipLaunchKernelGGL(k_zero,  dim3(NN / 256), dim3(256), 0, stream, cnt);
  hipLaunchKernelGGL(k_count, dim3(NE / 1024), dim3(256), 0, stream, dst, cnt);
  hipLaunchKernelGGL(k_scan1, dim3(512), dim3(256), 0, stream, cnt, partial);
  hipLaunchKernelGGL(k_scan2, dim3(1), dim3(512), 0, stream, partial);
  hipLaunchKernelGGL(k_scan3, dim3(512), dim3(256), 0, stream, cnt, partial, row_ptr, dinv, cursor);
  hipLaunchKernelGGL(k_fill,  dim3(NE / 512), dim3(256), 0, stream, src, dst, cursor, csr);
  hipLaunchKernelGGL(k_cvt,   dim3(NN * 128 / 4 / 256), dim3(256), 0, stream, x, xb);
  hipLaunchKernelGGL(k_swizzle, dim3(128), dim3(256), 0, stream, W1, Wsw1);
  hipLaunchKernelGGL(k_swizzle, dim3(256), dim3(256), 0, stream, W2, Wsw2);

  // layer 1 (split in halves for profiler visibility)
  hipLaunchKernelGGL(agg_128, dim3(NN / 8), dim3(256), 0, stream, xb, row_ptr, csr, dinv, bufA, 0);
  hipLaunchKernelGGL(agg_128, dim3(NN / 8), dim3(256), 0, stream, xb, row_ptr, csr, dinv, bufA, NN / 2);
  hipLaunchKernelGGL(k_gemm<128>, dim3(NN / 256), dim3(512), 0, stream, bufA, Wsw1, b1, bufB);
  // layer 2
  hipLaunchKernelGGL(agg_256, dim3(NN / 8), dim3(256), 0, stream, bufB, row_ptr, csr, dinv, bufA, 0);
  hipLaunchKernelGGL(agg_256, dim3(NN / 8), dim3(256), 0, stream, bufB, row_ptr, csr, dinv, bufA, NN / 2);
  hipLaunchKernelGGL(k_gemm<256>, dim3(NN / 256), dim3(512), 0, stream, bufA, Wsw2, b2, bufB);
  // readout
  hipLaunchKernelGGL(k_final, dim3(8192 / 4), dim3(256), 0, stream, bufB, Wout, bout, out);
}

// Round 5
// 937.246 us; speedup vs baseline: 1.3576x; 1.1660x over previous
//
#include <hip/hip_runtime.h>
#include <stdint.h>

#define NN 131072
#define NE 4194304

typedef __bf16 bf16x8 __attribute__((ext_vector_type(8)));
typedef float  floatx4 __attribute__((ext_vector_type(4)));
typedef unsigned short u16x8 __attribute__((ext_vector_type(8)));

__device__ __forceinline__ float bf2f(unsigned short u) {
  union { unsigned int i; float f; } v; v.i = ((unsigned int)u) << 16; return v.f;
}
__device__ __forceinline__ unsigned short f2bf(float f) {
  union { float f; unsigned int i; } v; v.f = f;
  unsigned int r = v.i + 0x7fffu + ((v.i >> 16) & 1u);  // RNE
  return (unsigned short)(r >> 16);
}

// ---------------- CSR build ----------------

__global__ __launch_bounds__(256) void k_zero(int* __restrict__ cnt) {
  cnt[blockIdx.x * 256 + threadIdx.x] = 0;
}

// 4 edges/thread; atomic return value IS the edge's rank within its dst bucket
__global__ __launch_bounds__(256) void k_count(const int* __restrict__ dst,
                                               int* __restrict__ cnt,
                                               int* __restrict__ rank) {
  const int t = blockIdx.x * 256 + threadIdx.x;
  const int4 d = ((const int4*)dst)[t];
  int4 r;
  r.x = atomicAdd(&cnt[d.x], 1);
  r.y = atomicAdd(&cnt[d.y], 1);
  r.z = atomicAdd(&cnt[d.z], 1);
  r.w = atomicAdd(&cnt[d.w], 1);
  ((int4*)rank)[t] = r;
}

// block sums: 512 blocks x 256 thr
__global__ __launch_bounds__(256) void k_scan1(const int* __restrict__ cnt,
                                               int* __restrict__ partial) {
  __shared__ int red[4];
  const int t = threadIdx.x;
  int v = cnt[blockIdx.x * 256 + t];
#pragma unroll
  for (int off = 32; off > 0; off >>= 1) v += __shfl_down(v, off);
  if ((t & 63) == 0) red[t >> 6] = v;
  __syncthreads();
  if (t == 0) partial[blockIdx.x] = red[0] + red[1] + red[2] + red[3];
}

// exclusive scan of 512 partials, single block
__global__ __launch_bounds__(512) void k_scan2(int* __restrict__ partial) {
  __shared__ int sc[512];
  const int t = threadIdx.x;
  const int c = partial[t];
  sc[t] = c;
  __syncthreads();
  for (int off = 1; off < 512; off <<= 1) {
    int v = (t >= off) ? sc[t - off] : 0;
    __syncthreads();
    sc[t] += v;
    __syncthreads();
  }
  partial[t] = sc[t] - c;  // exclusive
}

// row_ptr + dinv in one pass
__global__ __launch_bounds__(256) void k_scan3(const int* __restrict__ cnt,
                                               const int* __restrict__ partial,
                                               int* __restrict__ row_ptr,
                                               float* __restrict__ dinv) {
  __shared__ int sc[256];
  const int t = threadIdx.x;
  const int i = blockIdx.x * 256 + t;
  const int c = cnt[i];
  sc[t] = c;
  __syncthreads();
  for (int off = 1; off < 256; off <<= 1) {
    int v = (t >= off) ? sc[t - off] : 0;
    __syncthreads();
    sc[t] += v;
    __syncthreads();
  }
  const int row = partial[blockIdx.x] + sc[t] - c;  // exclusive
  row_ptr[i] = row;
  dinv[i] = rsqrtf((float)(c + 1));
  if (i == 0) row_ptr[NN] = NE;
}

// atomic-free fill: pos = row_ptr[dst] + rank  (unique by construction)
__global__ __launch_bounds__(256) void k_fill(const int* __restrict__ src,
                                              const int* __restrict__ dst,
                                              const int* __restrict__ rank,
                                              const int* __restrict__ row_ptr,
                                              int* __restrict__ csr) {
  const int t = blockIdx.x * 256 + threadIdx.x;
  const int4 s = ((const int4*)src)[t];
  const int4 d = ((const int4*)dst)[t];
  const int4 r = ((const int4*)rank)[t];
  const int p0 = row_ptr[d.x] + r.x;
  const int p1 = row_ptr[d.y] + r.y;
  const int p2 = row_ptr[d.z] + r.z;
  const int p3 = row_ptr[d.w] + r.w;
  csr[p0] = s.x;
  csr[p1] = s.y;
  csr[p2] = s.z;
  csr[p3] = s.w;
}

// ---------------- x fp32 -> bf16 ----------------
__global__ __launch_bounds__(256) void k_cvt(const float* __restrict__ X,
                                             unsigned short* __restrict__ Xb) {
  const int t = blockIdx.x * 256 + threadIdx.x;
  const float4 v = ((const float4*)X)[t];
  ushort4 o;
  o.x = f2bf(v.x); o.y = f2bf(v.y); o.z = f2bf(v.z); o.w = f2bf(v.w);
  ((ushort4*)Xb)[t] = o;
}

// ---------------- W swizzle (fp32 -> bf16, MFMA B-fragment order) ----------------
__global__ __launch_bounds__(256) void k_swizzle(const float* __restrict__ W,
                                                 unsigned short* __restrict__ Wsw) {
  const int t = blockIdx.x * 256 + threadIdx.x;  // t < K*256
  const int k = t >> 8, n = t & 255;
  const int s = ((k >> 5) * 16 + (n >> 4)) * 512 + ((k >> 3) & 3) * 128 + (n & 15) * 8 + (k & 7);
  Wsw[s] = f2bf(W[t]);
}

// ---------------- aggregation, F=128 ----------------
__global__ __launch_bounds__(256) void agg_128(const unsigned short* __restrict__ X,
                                               const int* __restrict__ row_ptr,
                                               const int* __restrict__ csr,
                                               const float* __restrict__ dinv,
                                               unsigned short* __restrict__ Y,
                                               int node_base) {
  const int lane = threadIdx.x & 63;
  const int node = node_base + ((blockIdx.x * blockDim.x + threadIdx.x) >> 6);
  const int sub = lane >> 4;   // 0..3
  const int fl = lane & 15;
  const int start = row_ptr[node];
  const int end = row_ptr[node + 1];
  const float di = dinv[node];
  float a[8] = {0.f, 0.f, 0.f, 0.f, 0.f, 0.f, 0.f, 0.f};
  const unsigned short* Xf = X + fl * 8;

  for (int e = start; e < end; e += 64) {
    const int nload = min(end - e, 64);
    int s_l = node;
    float w_l = 0.0f;
    if (lane < nload) {
      s_l = __builtin_nontemporal_load(&csr[e + lane]);  // streamed once: keep out of L2
      w_l = dinv[s_l];
    }
    for (int j = 0; j < nload; j += 16) {
      const int i0 = j + sub, i1 = j + 4 + sub, i2 = j + 8 + sub, i3 = j + 12 + sub;  // <= 63
      const int s0 = __shfl(s_l, i0); const float w0 = __shfl(w_l, i0);
      const int s1 = __shfl(s_l, i1); const float w1 = __shfl(w_l, i1);
      const int s2 = __shfl(s_l, i2); const float w2 = __shfl(w_l, i2);
      const int s3 = __shfl(s_l, i3); const float w3 = __shfl(w_l, i3);
      const u16x8 r0 = *(const u16x8*)(Xf + (size_t)s0 * 128);
      const u16x8 r1 = *(const u16x8*)(Xf + (size_t)s1 * 128);
      const u16x8 r2 = *(const u16x8*)(Xf + (size_t)s2 * 128);
      const u16x8 r3 = *(const u16x8*)(Xf + (size_t)s3 * 128);
#pragma unroll
      for (int i = 0; i < 8; ++i) a[i] = fmaf(w0, bf2f(r0[i]), a[i]);
#pragma unroll
      for (int i = 0; i < 8; ++i) a[i] = fmaf(w1, bf2f(r1[i]), a[i]);
#pragma unroll
      for (int i = 0; i < 8; ++i) a[i] = fmaf(w2, bf2f(r2[i]), a[i]);
#pragma unroll
      for (int i = 0; i < 8; ++i) a[i] = fmaf(w3, bf2f(r3[i]), a[i]);
    }
  }
#pragma unroll
  for (int i = 0; i < 8; ++i) a[i] += __shfl_xor(a[i], 16);
#pragma unroll
  for (int i = 0; i < 8; ++i) a[i] += __shfl_xor(a[i], 32);
  const u16x8 sv = *(const u16x8*)(Xf + (size_t)node * 128);
#pragma unroll
  for (int i = 0; i < 8; ++i) a[i] = fmaf(di, bf2f(sv[i]), a[i]);
  if (sub == 0) {
    u16x8 o;
#pragma unroll
    for (int i = 0; i < 8; ++i) o[i] = f2bf(di * a[i]);
    *(u16x8*)(Y + (size_t)node * 128 + fl * 8) = o;
  }
}

// ---------------- aggregation, F=256 ----------------
__global__ __launch_bounds__(256) void agg_256(const unsigned short* __restrict__ X,
                                               const int* __restrict__ row_ptr,
                                               const int* __restrict__ csr,
                                               const float* __restrict__ dinv,
                                               unsigned short* __restrict__ Y,
                                               int node_base) {
  const int lane = threadIdx.x & 63;
  const int node = node_base + ((blockIdx.x * blockDim.x + threadIdx.x) >> 6);
  const int sub = lane >> 5;   // 0/1
  const int fl = lane & 31;
  const int start = row_ptr[node];
  const int end = row_ptr[node + 1];
  const float di = dinv[node];
  float a[8] = {0.f, 0.f, 0.f, 0.f, 0.f, 0.f, 0.f, 0.f};
  const unsigned short* Xf = X + fl * 8;

  for (int e = start; e < end; e += 64) {
    const int nload = min(end - e, 64);
    int s_l = node;
    float w_l = 0.0f;
    if (lane < nload) {
      s_l = __builtin_nontemporal_load(&csr[e + lane]);
      w_l = dinv[s_l];
    }
    for (int j = 0; j < nload; j += 8) {
      const int i0 = j + sub, i1 = j + 2 + sub, i2 = j + 4 + sub, i3 = j + 6 + sub;  // <= 63
      const int s0 = __shfl(s_l, i0); const float w0 = __shfl(w_l, i0);
      const int s1 = __shfl(s_l, i1); const float w1 = __shfl(w_l, i1);
      const int s2 = __shfl(s_l, i2); const float w2 = __shfl(w_l, i2);
      const int s3 = __shfl(s_l, i3); const float w3 = __shfl(w_l, i3);
      const u16x8 r0 = *(const u16x8*)(Xf + (size_t)s0 * 256);
      const u16x8 r1 = *(const u16x8*)(Xf + (size_t)s1 * 256);
      const u16x8 r2 = *(const u16x8*)(Xf + (size_t)s2 * 256);
      const u16x8 r3 = *(const u16x8*)(Xf + (size_t)s3 * 256);
#pragma unroll
      for (int i = 0; i < 8; ++i) a[i] = fmaf(w0, bf2f(r0[i]), a[i]);
#pragma unroll
      for (int i = 0; i < 8; ++i) a[i] = fmaf(w1, bf2f(r1[i]), a[i]);
#pragma unroll
      for (int i = 0; i < 8; ++i) a[i] = fmaf(w2, bf2f(r2[i]), a[i]);
#pragma unroll
      for (int i = 0; i < 8; ++i) a[i] = fmaf(w3, bf2f(r3[i]), a[i]);
    }
  }
#pragma unroll
  for (int i = 0; i < 8; ++i) a[i] += __shfl_xor(a[i], 32);
  const u16x8 sv = *(const u16x8*)(Xf + (size_t)node * 256);
#pragma unroll
  for (int i = 0; i < 8; ++i) a[i] = fmaf(di, bf2f(sv[i]), a[i]);
  if (sub == 0) {
    u16x8 o;
#pragma unroll
    for (int i = 0; i < 8; ++i) o[i] = f2bf(di * a[i]);
    *(u16x8*)(Y + (size_t)node * 256 + fl * 8) = o;
  }
}

// ---------------- GEMM: out = relu(A[M,K](bf16) @ W[K,256](bf16) + b(fp32)), bf16 out ----------------
template <int K>  // 128 or 256
__global__ __launch_bounds__(512) void k_gemm(const unsigned short* __restrict__ A,
                                              const unsigned short* __restrict__ Wsw,
                                              const float* __restrict__ bias,
                                              unsigned short* __restrict__ out) {
  __shared__ unsigned short lW[128 * 256];  // 64 KB: one K-half of swizzled W
  const int tid = threadIdx.x;
  const int wave = tid >> 6;
  const int lane = tid & 63;
  const int q = lane >> 4;
  const int m16 = lane & 15;
  const size_t baseM = (size_t)blockIdx.x * 256;

  floatx4 acc[2][16];
#pragma unroll
  for (int t = 0; t < 2; ++t)
#pragma unroll
    for (int nt = 0; nt < 16; ++nt) acc[t][nt] = (floatx4){0.f, 0.f, 0.f, 0.f};

  const size_t rowA0 = baseM + wave * 32 + m16;
  const size_t rowA1 = rowA0 + 16;

  for (int half = 0; half < K / 128; ++half) {
    __syncthreads();
    const uint4* gsrc = (const uint4*)(Wsw + half * 32768);
    uint4* ldst = (uint4*)lW;
#pragma unroll
    for (int i = 0; i < 8; ++i) ldst[i * 512 + tid] = gsrc[i * 512 + tid];
    __syncthreads();

#pragma unroll
    for (int kc = 0; kc < 4; ++kc) {
      const int koff = half * 128 + kc * 32 + q * 8;
      const bf16x8 av0 = *(const bf16x8*)(A + rowA0 * K + koff);
      const bf16x8 av1 = *(const bf16x8*)(A + rowA1 * K + koff);
#pragma unroll
      for (int nt = 0; nt < 16; ++nt) {
        const bf16x8 bv = *(const bf16x8*)(&lW[(kc * 16 + nt) * 512 + lane * 8]);
        acc[0][nt] = __builtin_amdgcn_mfma_f32_16x16x32_bf16(av0, bv, acc[0][nt], 0, 0, 0);
        acc[1][nt] = __builtin_amdgcn_mfma_f32_16x16x32_bf16(av1, bv, acc[1][nt], 0, 0, 0);
      }
    }
  }
  const int rq = (lane >> 4) * 4;
#pragma unroll
  for (int t = 0; t < 2; ++t) {
#pragma unroll
    for (int nt = 0; nt < 16; ++nt) {
      const int col = nt * 16 + m16;
      const float bv = bias[col];
#pragma unroll
      for (int r = 0; r < 4; ++r) {
        const size_t row = baseM + wave * 32 + t * 16 + rq + r;
        float v = acc[t][nt][r] + bv;
        v = fmaxf(v, 0.0f);
        out[row * 256 + col] = f2bf(v);
      }
    }
  }
}

// ---------------- readout ----------------
__global__ __launch_bounds__(256) void k_final(const unsigned short* __restrict__ Z,
                                               const float* __restrict__ Wout,
                                               const float* __restrict__ bout,
                                               float* __restrict__ out) {
  const int lane = threadIdx.x & 63;
  const int g = (blockIdx.x * blockDim.x + threadIdx.x) >> 6;  // 0..8191
  const unsigned short* z = Z + (size_t)g * 4096;
  float acc = 0.f;
#pragma unroll
  for (int it = 0; it < 16; ++it) {
    const int idx = (it * 64 + lane) * 4;
    const ushort4 zv = *(const ushort4*)(z + idx);
    const float4 wv = *(const float4*)(Wout + idx);
    acc = fmaf(bf2f(zv.x), wv.x, acc);
    acc = fmaf(bf2f(zv.y), wv.y, acc);
    acc = fmaf(bf2f(zv.z), wv.z, acc);
    acc = fmaf(bf2f(zv.w), wv.w, acc);
  }
#pragma unroll
  for (int off = 32; off > 0; off >>= 1) acc += __shfl_down(acc, off);
  if (lane == 0) out[g] = acc + bout[0];
}

extern "C" void kernel_launch(void* const* d_in, const int* in_sizes, int n_in,
                              void* d_out, int out_size, void* d_ws, size_t ws_size,
                              hipStream_t stream) {
  const float* x    = (const float*)d_in[0];  // [N,128] fp32
  const int*   ei   = (const int*)d_in[1];    // [2,E] int32
  const float* W1   = (const float*)d_in[2];  // [128,256] fp32
  const float* b1   = (const float*)d_in[3];
  const float* W2   = (const float*)d_in[4];  // [256,256] fp32
  const float* b2   = (const float*)d_in[5];
  const float* Wout = (const float*)d_in[6];  // [4096] fp32
  const float* bout = (const float*)d_in[7];
  float* out = (float*)d_out;

  char* ws = (char*)d_ws;
  size_t off = 0;
  auto alloc = [&](size_t bytes) {
    char* p = ws + off;
    off += (bytes + 511) & ~(size_t)511;
    return p;
  };
  int*            row_ptr = (int*)alloc(((size_t)NN + 1) * 4);
  int*            cnt     = (int*)alloc((size_t)NN * 4);
  float*          dinv    = (float*)alloc((size_t)NN * 4);
  int*            partial = (int*)alloc(512 * 4);
  int*            rank    = (int*)alloc((size_t)NE * 4);
  int*            csr     = (int*)alloc((size_t)NE * 4);
  unsigned short* Wsw1    = (unsigned short*)alloc(128 * 256 * 2);
  unsigned short* Wsw2    = (unsigned short*)alloc(256 * 256 * 2);
  unsigned short* xb      = (unsigned short*)alloc((size_t)NN * 128 * 2);
  unsigned short* bufA    = (unsigned short*)alloc((size_t)NN * 256 * 2);
  unsigned short* bufB    = (unsigned short*)alloc((size_t)NN * 256 * 2);
  (void)in_sizes; (void)n_in; (void)out_size; (void)ws_size;

  const int* src = ei;
  const int* dst = ei + NE;

  hipLaunchKernelGGL(k_zero,  dim3(NN / 256), dim3(256), 0, stream, cnt);
  hipLaunchKernelGGL(k_count, dim3(NE / 1024), dim3(256), 0, stream, dst, cnt, rank);
  hipLaunchKernelGGL(k_scan1, dim3(512), dim3(256), 0, stream, cnt, partial);
  hipLaunchKernelGGL(k_scan2, dim3(1), dim3(512), 0, stream, partial);
  hipLaunchKernelGGL(k_scan3, dim3(512), dim3(256), 0, stream, cnt, partial, row_ptr, dinv);
  hipLaunchKernelGGL(k_fill,  dim3(NE / 1024), dim3(256), 0, stream, src, dst, rank, row_ptr, csr);
  hipLaunchKernelGGL(k_cvt,   dim3(NN * 128 / 4 / 256), dim3(256), 0, stream, x, xb);
  hipLaunchKernelGGL(k_swizzle, dim3(128), dim3(256), 0, stream, W1, Wsw1);
  hipLaunchKernelGGL(k_swizzle, dim3(256), dim3(256), 0, stream, W2, Wsw2);

  // layer 1 (split in halves for profiler visibility)
  hipLaunchKernelGGL(agg_128, dim3(NN / 8), dim3(256), 0, stream, xb, row_ptr, csr, dinv, bufA, 0);
  hipLaunchKernelGGL(agg_128, dim3(NN / 8), dim3(256), 0, stream, xb, row_ptr, csr, dinv, bufA, NN / 2);
  hipLaunchKernelGGL(k_gemm<128>, dim3(NN / 256), dim3(512), 0, stream, bufA, Wsw1, b1, bufB);
  // layer 2
  hipLaunchKernelGGL(agg_256, dim3(NN / 8), dim3(256), 0, stream, bufB, row_ptr, csr, dinv, bufA, 0);
  hipLaunchKernelGGL(agg_256, dim3(NN / 8), dim3(256), 0, stream, bufB, row_ptr, csr, dinv, bufA, NN / 2);
  hipLaunchKernelGGL(k_gemm<256>, dim3(NN / 256), dim3(512), 0, stream, bufA, Wsw2, b2, bufB);
  // readout
  hipLaunchKernelGGL(k_final, dim3(8192 / 4), dim3(256), 0, stream, bufB, Wout, bout, out);
}

// Round 6
// 756.210 us; speedup vs baseline: 1.6827x; 1.2394x over previous
//
#include <hip/hip_runtime.h>
#include <stdint.h>

#define NN 131072
#define NE 4194304
#define BKT 256      // buckets (512 nodes each)
#define BKT_SH 9
#define BCAP 20480   // bucket capacity; mean 16384, sigma ~128

typedef __bf16 bf16x8 __attribute__((ext_vector_type(8)));
typedef float  floatx4 __attribute__((ext_vector_type(4)));
typedef unsigned short u16x8 __attribute__((ext_vector_type(8)));

__device__ __forceinline__ float bf2f(unsigned short u) {
  union { unsigned int i; float f; } v; v.i = ((unsigned int)u) << 16; return v.f;
}
__device__ __forceinline__ unsigned short f2bf(float f) {
  union { float f; unsigned int i; } v; v.f = f;
  unsigned int r = v.i + 0x7fffu + ((v.i >> 16) & 1u);  // RNE
  return (unsigned short)(r >> 16);
}

// ---------------- CSR build: LDS-histogram bucketing ----------------

__global__ __launch_bounds__(256) void k_bzero(int* __restrict__ bktCnt) {
  bktCnt[threadIdx.x] = 0;
}

// pass A: bin edges into 256 dst-buckets; packed edge = (src<<9)|(dst&511)
__global__ __launch_bounds__(1024) void k_bucket(const int* __restrict__ src,
                                                 const int* __restrict__ dst,
                                                 int* __restrict__ bktCnt,
                                                 unsigned int* __restrict__ bktBuf) {
  __shared__ int hist[BKT];
  __shared__ int base[BKT];
  const int t = threadIdx.x;
  if (t < BKT) hist[t] = 0;
  __syncthreads();
  const int e0 = (blockIdx.x * 1024 + t);
  const int4 s = ((const int4*)src)[e0];
  const int4 d = ((const int4*)dst)[e0];
  const int b0 = ((unsigned)d.x) >> BKT_SH, b1 = ((unsigned)d.y) >> BKT_SH;
  const int b2 = ((unsigned)d.z) >> BKT_SH, b3 = ((unsigned)d.w) >> BKT_SH;
  const int r0 = atomicAdd(&hist[b0], 1);
  const int r1 = atomicAdd(&hist[b1], 1);
  const int r2 = atomicAdd(&hist[b2], 1);
  const int r3 = atomicAdd(&hist[b3], 1);
  __syncthreads();
  if (t < BKT) base[t] = atomicAdd(&bktCnt[t], hist[t]);  // 256 global atomics/block
  __syncthreads();
  const unsigned p0 = (((unsigned)s.x) << BKT_SH) | (d.x & 511);
  const unsigned p1 = (((unsigned)s.y) << BKT_SH) | (d.y & 511);
  const unsigned p2 = (((unsigned)s.z) << BKT_SH) | (d.z & 511);
  const unsigned p3 = (((unsigned)s.w) << BKT_SH) | (d.w & 511);
  bktBuf[(size_t)b0 * BCAP + base[b0] + r0] = p0;
  bktBuf[(size_t)b1 * BCAP + base[b1] + r1] = p1;
  bktBuf[(size_t)b2 * BCAP + base[b2] + r2] = p2;
  bktBuf[(size_t)b3 * BCAP + base[b3] + r3] = p3;
}

// pass B: one block per bucket -> counts, row_ptr, dinv, csr fill
__global__ __launch_bounds__(1024) void k_csr(const int* __restrict__ bktCnt,
                                              const unsigned int* __restrict__ bktBuf,
                                              int* __restrict__ row_ptr,
                                              float* __restrict__ dinv,
                                              int* __restrict__ csr) {
  __shared__ int bsum[BKT];
  __shared__ int hist[512];
  __shared__ int sc[512];
  __shared__ int cur[512];
  const int b = blockIdx.x;
  const int t = threadIdx.x;
  if (t < BKT) bsum[t] = bktCnt[t];
  if (t < 512) hist[t] = 0;
  __syncthreads();
  // inclusive scan of bucket sizes (256)
  for (int off = 1; off < BKT; off <<= 1) {
    int v = 0;
    if (t < BKT && t >= off) v = bsum[t - off];
    __syncthreads();
    if (t < BKT) bsum[t] += v;
    __syncthreads();
  }
  const int sz = bktCnt[b];
  const int csrBase = bsum[b] - sz;  // exclusive prefix
  const unsigned int* eb = bktBuf + (size_t)b * BCAP;
  // local node histogram
  for (int i = t; i < sz; i += 1024) atomicAdd(&hist[eb[i] & 511], 1);
  __syncthreads();
  if (t < 512) sc[t] = hist[t];
  __syncthreads();
  for (int off = 1; off < 512; off <<= 1) {
    int v = 0;
    if (t < 512 && t >= off) v = sc[t - off];
    __syncthreads();
    if (t < 512) sc[t] += v;
    __syncthreads();
  }
  if (t < 512) {
    const int ex = csrBase + sc[t] - hist[t];  // exclusive
    row_ptr[b * 512 + t] = ex;
    cur[t] = ex;
    dinv[b * 512 + t] = rsqrtf((float)(hist[t] + 1));
  }
  if (b == BKT - 1 && t == 0) row_ptr[NN] = NE;
  __syncthreads();
  // fill csr (bucket csr region = 64 KB -> L2-resident writes)
  for (int i = t; i < sz; i += 1024) {
    const unsigned e = eb[i];
    csr[atomicAdd(&cur[e & 511], 1)] = (int)(e >> BKT_SH);
  }
}

// ---------------- x fp32 -> bf16 ----------------
__global__ __launch_bounds__(256) void k_cvt(const float* __restrict__ X,
                                             unsigned short* __restrict__ Xb) {
  const int t = blockIdx.x * 256 + threadIdx.x;
  const float4 v = ((const float4*)X)[t];
  ushort4 o;
  o.x = f2bf(v.x); o.y = f2bf(v.y); o.z = f2bf(v.z); o.w = f2bf(v.w);
  ((ushort4*)Xb)[t] = o;
}

// ---------------- W swizzle (fp32 -> bf16, MFMA B-fragment order) ----------------
__global__ __launch_bounds__(256) void k_swizzle(const float* __restrict__ W,
                                                 unsigned short* __restrict__ Wsw) {
  const int t = blockIdx.x * 256 + threadIdx.x;  // t < K*256
  const int k = t >> 8, n = t & 255;
  const int s = ((k >> 5) * 16 + (n >> 4)) * 512 + ((k >> 3) & 3) * 128 + (n & 15) * 8 + (k & 7);
  Wsw[s] = f2bf(W[t]);
}

// ---------------- aggregation, F=128 ----------------
__global__ __launch_bounds__(256) void agg_128(const unsigned short* __restrict__ X,
                                               const int* __restrict__ row_ptr,
                                               const int* __restrict__ csr,
                                               const float* __restrict__ dinv,
                                               unsigned short* __restrict__ Y,
                                               int node_base) {
  const int lane = threadIdx.x & 63;
  const int node = node_base + ((blockIdx.x * blockDim.x + threadIdx.x) >> 6);
  const int sub = lane >> 4;   // 0..3
  const int fl = lane & 15;
  const int start = row_ptr[node];
  const int end = row_ptr[node + 1];
  const float di = dinv[node];
  float a[8] = {0.f, 0.f, 0.f, 0.f, 0.f, 0.f, 0.f, 0.f};
  const unsigned short* Xf = X + fl * 8;

  for (int e = start; e < end; e += 64) {
    const int nload = min(end - e, 64);
    int s_l = node;
    float w_l = 0.0f;
    if (lane < nload) {
      s_l = __builtin_nontemporal_load(&csr[e + lane]);
      w_l = dinv[s_l];
    }
    for (int j = 0; j < nload; j += 16) {
      const int i0 = j + sub, i1 = j + 4 + sub, i2 = j + 8 + sub, i3 = j + 12 + sub;
      const int s0 = __shfl(s_l, i0); const float w0 = __shfl(w_l, i0);
      const int s1 = __shfl(s_l, i1); const float w1 = __shfl(w_l, i1);
      const int s2 = __shfl(s_l, i2); const float w2 = __shfl(w_l, i2);
      const int s3 = __shfl(s_l, i3); const float w3 = __shfl(w_l, i3);
      const u16x8 r0 = *(const u16x8*)(Xf + (size_t)s0 * 128);
      const u16x8 r1 = *(const u16x8*)(Xf + (size_t)s1 * 128);
      const u16x8 r2 = *(const u16x8*)(Xf + (size_t)s2 * 128);
      const u16x8 r3 = *(const u16x8*)(Xf + (size_t)s3 * 128);
#pragma unroll
      for (int i = 0; i < 8; ++i) a[i] = fmaf(w0, bf2f(r0[i]), a[i]);
#pragma unroll
      for (int i = 0; i < 8; ++i) a[i] = fmaf(w1, bf2f(r1[i]), a[i]);
#pragma unroll
      for (int i = 0; i < 8; ++i) a[i] = fmaf(w2, bf2f(r2[i]), a[i]);
#pragma unroll
      for (int i = 0; i < 8; ++i) a[i] = fmaf(w3, bf2f(r3[i]), a[i]);
    }
  }
#pragma unroll
  for (int i = 0; i < 8; ++i) a[i] += __shfl_xor(a[i], 16);
#pragma unroll
  for (int i = 0; i < 8; ++i) a[i] += __shfl_xor(a[i], 32);
  const u16x8 sv = *(const u16x8*)(Xf + (size_t)node * 128);
#pragma unroll
  for (int i = 0; i < 8; ++i) a[i] = fmaf(di, bf2f(sv[i]), a[i]);
  if (sub == 0) {
    u16x8 o;
#pragma unroll
    for (int i = 0; i < 8; ++i) o[i] = f2bf(di * a[i]);
    *(u16x8*)(Y + (size_t)node * 128 + fl * 8) = o;
  }
}

// ---------------- aggregation, F=256 ----------------
__global__ __launch_bounds__(256) void agg_256(const unsigned short* __restrict__ X,
                                               const int* __restrict__ row_ptr,
                                               const int* __restrict__ csr,
                                               const float* __restrict__ dinv,
                                               unsigned short* __restrict__ Y,
                                               int node_base) {
  const int lane = threadIdx.x & 63;
  const int node = node_base + ((blockIdx.x * blockDim.x + threadIdx.x) >> 6);
  const int sub = lane >> 5;   // 0/1
  const int fl = lane & 31;
  const int start = row_ptr[node];
  const int end = row_ptr[node + 1];
  const float di = dinv[node];
  float a[8] = {0.f, 0.f, 0.f, 0.f, 0.f, 0.f, 0.f, 0.f};
  const unsigned short* Xf = X + fl * 8;

  for (int e = start; e < end; e += 64) {
    const int nload = min(end - e, 64);
    int s_l = node;
    float w_l = 0.0f;
    if (lane < nload) {
      s_l = __builtin_nontemporal_load(&csr[e + lane]);
      w_l = dinv[s_l];
    }
    for (int j = 0; j < nload; j += 8) {
      const int i0 = j + sub, i1 = j + 2 + sub, i2 = j + 4 + sub, i3 = j + 6 + sub;
      const int s0 = __shfl(s_l, i0); const float w0 = __shfl(w_l, i0);
      const int s1 = __shfl(s_l, i1); const float w1 = __shfl(w_l, i1);
      const int s2 = __shfl(s_l, i2); const float w2 = __shfl(w_l, i2);
      const int s3 = __shfl(s_l, i3); const float w3 = __shfl(w_l, i3);
      const u16x8 r0 = *(const u16x8*)(Xf + (size_t)s0 * 256);
      const u16x8 r1 = *(const u16x8*)(Xf + (size_t)s1 * 256);
      const u16x8 r2 = *(const u16x8*)(Xf + (size_t)s2 * 256);
      const u16x8 r3 = *(const u16x8*)(Xf + (size_t)s3 * 256);
#pragma unroll
      for (int i = 0; i < 8; ++i) a[i] = fmaf(w0, bf2f(r0[i]), a[i]);
#pragma unroll
      for (int i = 0; i < 8; ++i) a[i] = fmaf(w1, bf2f(r1[i]), a[i]);
#pragma unroll
      for (int i = 0; i < 8; ++i) a[i] = fmaf(w2, bf2f(r2[i]), a[i]);
#pragma unroll
      for (int i = 0; i < 8; ++i) a[i] = fmaf(w3, bf2f(r3[i]), a[i]);
    }
  }
#pragma unroll
  for (int i = 0; i < 8; ++i) a[i] += __shfl_xor(a[i], 32);
  const u16x8 sv = *(const u16x8*)(Xf + (size_t)node * 256);
#pragma unroll
  for (int i = 0; i < 8; ++i) a[i] = fmaf(di, bf2f(sv[i]), a[i]);
  if (sub == 0) {
    u16x8 o;
#pragma unroll
    for (int i = 0; i < 8; ++i) o[i] = f2bf(di * a[i]);
    *(u16x8*)(Y + (size_t)node * 256 + fl * 8) = o;
  }
}

// ---------------- GEMM: out = relu(A[M,K](bf16) @ W[K,256](bf16) + b(fp32)), bf16 out ----------------
template <int K>  // 128 or 256
__global__ __launch_bounds__(512) void k_gemm(const unsigned short* __restrict__ A,
                                              const unsigned short* __restrict__ Wsw,
                                              const float* __restrict__ bias,
                                              unsigned short* __restrict__ out) {
  __shared__ unsigned short lW[128 * 256];  // 64 KB: one K-half of swizzled W
  const int tid = threadIdx.x;
  const int wave = tid >> 6;
  const int lane = tid & 63;
  const int q = lane >> 4;
  const int m16 = lane & 15;
  const size_t baseM = (size_t)blockIdx.x * 256;

  floatx4 acc[2][16];
#pragma unroll
  for (int t = 0; t < 2; ++t)
#pragma unroll
    for (int nt = 0; nt < 16; ++nt) acc[t][nt] = (floatx4){0.f, 0.f, 0.f, 0.f};

  const size_t rowA0 = baseM + wave * 32 + m16;
  const size_t rowA1 = rowA0 + 16;

  for (int half = 0; half < K / 128; ++half) {
    __syncthreads();
    const uint4* gsrc = (const uint4*)(Wsw + half * 32768);
    uint4* ldst = (uint4*)lW;
#pragma unroll
    for (int i = 0; i < 8; ++i) ldst[i * 512 + tid] = gsrc[i * 512 + tid];
    __syncthreads();

#pragma unroll
    for (int kc = 0; kc < 4; ++kc) {
      const int koff = half * 128 + kc * 32 + q * 8;
      const bf16x8 av0 = *(const bf16x8*)(A + rowA0 * K + koff);
      const bf16x8 av1 = *(const bf16x8*)(A + rowA1 * K + koff);
#pragma unroll
      for (int nt = 0; nt < 16; ++nt) {
        const bf16x8 bv = *(const bf16x8*)(&lW[(kc * 16 + nt) * 512 + lane * 8]);
        acc[0][nt] = __builtin_amdgcn_mfma_f32_16x16x32_bf16(av0, bv, acc[0][nt], 0, 0, 0);
        acc[1][nt] = __builtin_amdgcn_mfma_f32_16x16x32_bf16(av1, bv, acc[1][nt], 0, 0, 0);
      }
    }
  }
  const int rq = (lane >> 4) * 4;
#pragma unroll
  for (int t = 0; t < 2; ++t) {
#pragma unroll
    for (int nt = 0; nt < 16; ++nt) {
      const int col = nt * 16 + m16;
      const float bv = bias[col];
#pragma unroll
      for (int r = 0; r < 4; ++r) {
        const size_t row = baseM + wave * 32 + t * 16 + rq + r;
        float v = acc[t][nt][r] + bv;
        v = fmaxf(v, 0.0f);
        out[row * 256 + col] = f2bf(v);
      }
    }
  }
}

// ---------------- readout ----------------
__global__ __launch_bounds__(256) void k_final(const unsigned short* __restrict__ Z,
                                               const float* __restrict__ Wout,
                                               const float* __restrict__ bout,
                                               float* __restrict__ out) {
  const int lane = threadIdx.x & 63;
  const int g = (blockIdx.x * blockDim.x + threadIdx.x) >> 6;  // 0..8191
  const unsigned short* z = Z + (size_t)g * 4096;
  float acc = 0.f;
#pragma unroll
  for (int it = 0; it < 16; ++it) {
    const int idx = (it * 64 + lane) * 4;
    const ushort4 zv = *(const ushort4*)(z + idx);
    const float4 wv = *(const float4*)(Wout + idx);
    acc = fmaf(bf2f(zv.x), wv.x, acc);
    acc = fmaf(bf2f(zv.y), wv.y, acc);
    acc = fmaf(bf2f(zv.z), wv.z, acc);
    acc = fmaf(bf2f(zv.w), wv.w, acc);
  }
#pragma unroll
  for (int off = 32; off > 0; off >>= 1) acc += __shfl_down(acc, off);
  if (lane == 0) out[g] = acc + bout[0];
}

extern "C" void kernel_launch(void* const* d_in, const int* in_sizes, int n_in,
                              void* d_out, int out_size, void* d_ws, size_t ws_size,
                              hipStream_t stream) {
  const float* x    = (const float*)d_in[0];  // [N,128] fp32
  const int*   ei   = (const int*)d_in[1];    // [2,E] int32
  const float* W1   = (const float*)d_in[2];  // [128,256] fp32
  const float* b1   = (const float*)d_in[3];
  const float* W2   = (const float*)d_in[4];  // [256,256] fp32
  const float* b2   = (const float*)d_in[5];
  const float* Wout = (const float*)d_in[6];  // [4096] fp32
  const float* bout = (const float*)d_in[7];
  float* out = (float*)d_out;

  char* ws = (char*)d_ws;
  size_t off = 0;
  auto alloc = [&](size_t bytes) {
    char* p = ws + off;
    off += (bytes + 511) & ~(size_t)511;
    return p;
  };
  int*            row_ptr = (int*)alloc(((size_t)NN + 1) * 4);
  float*          dinv    = (float*)alloc((size_t)NN * 4);
  int*            bktCnt  = (int*)alloc(BKT * 4);
  unsigned int*   bktBuf  = (unsigned int*)alloc((size_t)BKT * BCAP * 4);  // 21 MB
  int*            csr     = (int*)alloc((size_t)NE * 4);
  unsigned short* Wsw1    = (unsigned short*)alloc(128 * 256 * 2);
  unsigned short* Wsw2    = (unsigned short*)alloc(256 * 256 * 2);
  unsigned short* xb      = (unsigned short*)alloc((size_t)NN * 128 * 2);
  unsigned short* bufA    = (unsigned short*)alloc((size_t)NN * 256 * 2);
  unsigned short* bufB    = (unsigned short*)alloc((size_t)NN * 256 * 2);
  (void)in_sizes; (void)n_in; (void)out_size; (void)ws_size;

  const int* src = ei;
  const int* dst = ei + NE;

  hipLaunchKernelGGL(k_bzero,  dim3(1), dim3(256), 0, stream, bktCnt);
  hipLaunchKernelGGL(k_bucket, dim3(NE / 4096), dim3(1024), 0, stream, src, dst, bktCnt, bktBuf);
  hipLaunchKernelGGL(k_csr,    dim3(BKT), dim3(1024), 0, stream, bktCnt, bktBuf, row_ptr, dinv, csr);
  hipLaunchKernelGGL(k_cvt,    dim3(NN * 128 / 4 / 256), dim3(256), 0, stream, x, xb);
  hipLaunchKernelGGL(k_swizzle, dim3(128), dim3(256), 0, stream, W1, Wsw1);
  hipLaunchKernelGGL(k_swizzle, dim3(256), dim3(256), 0, stream, W2, Wsw2);

  // layer 1 (split in halves for profiler visibility)
  hipLaunchKernelGGL(agg_128, dim3(NN / 8), dim3(256), 0, stream, xb, row_ptr, csr, dinv, bufA, 0);
  hipLaunchKernelGGL(agg_128, dim3(NN / 8), dim3(256), 0, stream, xb, row_ptr, csr, dinv, bufA, NN / 2);
  hipLaunchKernelGGL(k_gemm<128>, dim3(NN / 256), dim3(512), 0, stream, bufA, Wsw1, b1, bufB);
  // layer 2
  hipLaunchKernelGGL(agg_256, dim3(NN / 8), dim3(256), 0, stream, bufB, row_ptr, csr, dinv, bufA, 0);
  hipLaunchKernelGGL(agg_256, dim3(NN / 8), dim3(256), 0, stream, bufB, row_ptr, csr, dinv, bufA, NN / 2);
  hipLaunchKernelGGL(k_gemm<256>, dim3(NN / 256), dim3(512), 0, stream, bufA, Wsw2, b2, bufB);
  // readout
  hipLaunchKernelGGL(k_final, dim3(8192 / 4), dim3(256), 0, stream, bufB, Wout, bout, out);
}

// Round 7
// 733.709 us; speedup vs baseline: 1.7343x; 1.0307x over previous
//
#include <hip/hip_runtime.h>
#include <stdint.h>

#define NN 131072
#define NE 4194304
#define BKT 256      // buckets (512 nodes each)
#define BKT_SH 9
#define BCAP 20480   // bucket capacity; mean 16384, sigma ~128

typedef __bf16 bf16x8 __attribute__((ext_vector_type(8)));
typedef float  floatx4 __attribute__((ext_vector_type(4)));
typedef unsigned short u16x8 __attribute__((ext_vector_type(8)));

__device__ __forceinline__ float bf2f(unsigned short u) {
  union { unsigned int i; float f; } v; v.i = ((unsigned int)u) << 16; return v.f;
}
__device__ __forceinline__ unsigned short f2bf(float f) {
  union { float f; unsigned int i; } v; v.f = f;
  unsigned int r = v.i + 0x7fffu + ((v.i >> 16) & 1u);  // RNE
  return (unsigned short)(r >> 16);
}

// ---------------- CSR build: LDS-histogram bucketing ----------------

__global__ __launch_bounds__(256) void k_bzero(int* __restrict__ bktCnt) {
  bktCnt[threadIdx.x] = 0;
}

// pass A: bin edges into 256 dst-buckets; packed edge = (src<<9)|(dst&511)
__global__ __launch_bounds__(1024) void k_bucket(const int* __restrict__ src,
                                                 const int* __restrict__ dst,
                                                 int* __restrict__ bktCnt,
                                                 unsigned int* __restrict__ bktBuf) {
  __shared__ int hist[BKT];
  __shared__ int base[BKT];
  const int t = threadIdx.x;
  if (t < BKT) hist[t] = 0;
  __syncthreads();
  const int e0 = (blockIdx.x * 1024 + t);
  const int4 s = ((const int4*)src)[e0];
  const int4 d = ((const int4*)dst)[e0];
  const int b0 = ((unsigned)d.x) >> BKT_SH, b1 = ((unsigned)d.y) >> BKT_SH;
  const int b2 = ((unsigned)d.z) >> BKT_SH, b3 = ((unsigned)d.w) >> BKT_SH;
  const int r0 = atomicAdd(&hist[b0], 1);
  const int r1 = atomicAdd(&hist[b1], 1);
  const int r2 = atomicAdd(&hist[b2], 1);
  const int r3 = atomicAdd(&hist[b3], 1);
  __syncthreads();
  if (t < BKT) base[t] = atomicAdd(&bktCnt[t], hist[t]);  // 256 global atomics/block
  __syncthreads();
  const unsigned p0 = (((unsigned)s.x) << BKT_SH) | (d.x & 511);
  const unsigned p1 = (((unsigned)s.y) << BKT_SH) | (d.y & 511);
  const unsigned p2 = (((unsigned)s.z) << BKT_SH) | (d.z & 511);
  const unsigned p3 = (((unsigned)s.w) << BKT_SH) | (d.w & 511);
  bktBuf[(size_t)b0 * BCAP + base[b0] + r0] = p0;
  bktBuf[(size_t)b1 * BCAP + base[b1] + r1] = p1;
  bktBuf[(size_t)b2 * BCAP + base[b2] + r2] = p2;
  bktBuf[(size_t)b3 * BCAP + base[b3] + r3] = p3;
}

// pass B: one block per bucket -> counts, row_ptr, dinv, csr fill
__global__ __launch_bounds__(1024) void k_csr(const int* __restrict__ bktCnt,
                                              const unsigned int* __restrict__ bktBuf,
                                              int* __restrict__ row_ptr,
                                              float* __restrict__ dinv,
                                              int* __restrict__ csr) {
  __shared__ int bsum[BKT];
  __shared__ int hist[512];
  __shared__ int sc[512];
  __shared__ int cur[512];
  const int b = blockIdx.x;
  const int t = threadIdx.x;
  if (t < BKT) bsum[t] = bktCnt[t];
  if (t < 512) hist[t] = 0;
  __syncthreads();
  // inclusive scan of bucket sizes (256)
  for (int off = 1; off < BKT; off <<= 1) {
    int v = 0;
    if (t < BKT && t >= off) v = bsum[t - off];
    __syncthreads();
    if (t < BKT) bsum[t] += v;
    __syncthreads();
  }
  const int sz = bktCnt[b];
  const int csrBase = bsum[b] - sz;  // exclusive prefix
  const unsigned int* eb = bktBuf + (size_t)b * BCAP;
  // local node histogram
  for (int i = t; i < sz; i += 1024) atomicAdd(&hist[eb[i] & 511], 1);
  __syncthreads();
  if (t < 512) sc[t] = hist[t];
  __syncthreads();
  for (int off = 1; off < 512; off <<= 1) {
    int v = 0;
    if (t < 512 && t >= off) v = sc[t - off];
    __syncthreads();
    if (t < 512) sc[t] += v;
    __syncthreads();
  }
  if (t < 512) {
    const int ex = csrBase + sc[t] - hist[t];  // exclusive
    row_ptr[b * 512 + t] = ex;
    cur[t] = ex;
    dinv[b * 512 + t] = rsqrtf((float)(hist[t] + 1));
  }
  if (b == BKT - 1 && t == 0) row_ptr[NN] = NE;
  __syncthreads();
  // fill csr (bucket csr region = 64 KB -> L2-resident writes)
  for (int i = t; i < sz; i += 1024) {
    const unsigned e = eb[i];
    csr[atomicAdd(&cur[e & 511], 1)] = (int)(e >> BKT_SH);
  }
}

// ---------------- x fp32 -> bf16 ----------------
__global__ __launch_bounds__(256) void k_cvt(const float* __restrict__ X,
                                             unsigned short* __restrict__ Xb) {
  const int t = blockIdx.x * 256 + threadIdx.x;
  const float4 v = ((const float4*)X)[t];
  ushort4 o;
  o.x = f2bf(v.x); o.y = f2bf(v.y); o.z = f2bf(v.z); o.w = f2bf(v.w);
  ((ushort4*)Xb)[t] = o;
}

// ---------------- W swizzle (fp32 -> bf16, MFMA B-fragment order) ----------------
__global__ __launch_bounds__(256) void k_swizzle(const float* __restrict__ W,
                                                 unsigned short* __restrict__ Wsw) {
  const int t = blockIdx.x * 256 + threadIdx.x;  // t < K*256
  const int k = t >> 8, n = t & 255;
  const int s = ((k >> 5) * 16 + (n >> 4)) * 512 + ((k >> 3) & 3) * 128 + (n & 15) * 8 + (k & 7);
  Wsw[s] = f2bf(W[t]);
}

// ---------------- aggregation, feature-sliced pass ----------------
// One wave per node. LPR lanes per row gather LPR*8 contiguous feats starting
// at foff from rows of stride F. 64/LPR edge sub-groups, 4 gathers in flight.
// Separate dispatches per feature slice shrink the gather working set -> L2 hit rate.
template <int LPR>  // 16: slice=128 feats; 8: slice=64 feats
__global__ __launch_bounds__(256) void agg_h(const unsigned short* __restrict__ X,
                                             const int* __restrict__ row_ptr,
                                             const int* __restrict__ csr,
                                             const float* __restrict__ dinv,
                                             unsigned short* __restrict__ Y,
                                             int F, int foff) {
  constexpr int SUB = 64 / LPR;
  const int lane = threadIdx.x & 63;
  const int node = (blockIdx.x * blockDim.x + threadIdx.x) >> 6;
  const int sub = lane / LPR;
  const int fl = lane % LPR;
  const int start = row_ptr[node];
  const int end = row_ptr[node + 1];
  const float di = dinv[node];
  float a[8] = {0.f, 0.f, 0.f, 0.f, 0.f, 0.f, 0.f, 0.f};
  const unsigned short* Xf = X + foff + fl * 8;

  for (int e = start; e < end; e += 64) {
    const int nload = min(end - e, 64);
    int s_l = node;
    float w_l = 0.0f;
    if (lane < nload) {
      s_l = __builtin_nontemporal_load(&csr[e + lane]);
      w_l = dinv[s_l];
    }
    for (int j = 0; j < nload; j += 4 * SUB) {
      const int i0 = j + sub, i1 = j + SUB + sub, i2 = j + 2 * SUB + sub, i3 = j + 3 * SUB + sub;  // <= 63
      const int s0 = __shfl(s_l, i0); const float w0 = __shfl(w_l, i0);
      const int s1 = __shfl(s_l, i1); const float w1 = __shfl(w_l, i1);
      const int s2 = __shfl(s_l, i2); const float w2 = __shfl(w_l, i2);
      const int s3 = __shfl(s_l, i3); const float w3 = __shfl(w_l, i3);
      const u16x8 r0 = *(const u16x8*)(Xf + (size_t)s0 * F);
      const u16x8 r1 = *(const u16x8*)(Xf + (size_t)s1 * F);
      const u16x8 r2 = *(const u16x8*)(Xf + (size_t)s2 * F);
      const u16x8 r3 = *(const u16x8*)(Xf + (size_t)s3 * F);
#pragma unroll
      for (int i = 0; i < 8; ++i) a[i] = fmaf(w0, bf2f(r0[i]), a[i]);
#pragma unroll
      for (int i = 0; i < 8; ++i) a[i] = fmaf(w1, bf2f(r1[i]), a[i]);
#pragma unroll
      for (int i = 0; i < 8; ++i) a[i] = fmaf(w2, bf2f(r2[i]), a[i]);
#pragma unroll
      for (int i = 0; i < 8; ++i) a[i] = fmaf(w3, bf2f(r3[i]), a[i]);
    }
  }
#pragma unroll
  for (int off = LPR; off < 64; off <<= 1)
#pragma unroll
    for (int i = 0; i < 8; ++i) a[i] += __shfl_xor(a[i], off);
  const u16x8 sv = *(const u16x8*)(Xf + (size_t)node * F);
#pragma unroll
  for (int i = 0; i < 8; ++i) a[i] = fmaf(di, bf2f(sv[i]), a[i]);
  if (sub == 0) {
    u16x8 o;
#pragma unroll
    for (int i = 0; i < 8; ++i) o[i] = f2bf(di * a[i]);
    *(u16x8*)(Y + (size_t)node * F + foff + fl * 8) = o;
  }
}

// ---------------- GEMM: out = relu(A[M,K](bf16) @ W[K,256](bf16) + b(fp32)), bf16 out ----------------
template <int K>  // 128 or 256
__global__ __launch_bounds__(512) void k_gemm(const unsigned short* __restrict__ A,
                                              const unsigned short* __restrict__ Wsw,
                                              const float* __restrict__ bias,
                                              unsigned short* __restrict__ out) {
  __shared__ unsigned short lW[128 * 256];  // 64 KB: one K-half of swizzled W
  const int tid = threadIdx.x;
  const int wave = tid >> 6;
  const int lane = tid & 63;
  const int q = lane >> 4;
  const int m16 = lane & 15;
  const size_t baseM = (size_t)blockIdx.x * 256;

  floatx4 acc[2][16];
#pragma unroll
  for (int t = 0; t < 2; ++t)
#pragma unroll
    for (int nt = 0; nt < 16; ++nt) acc[t][nt] = (floatx4){0.f, 0.f, 0.f, 0.f};

  const size_t rowA0 = baseM + wave * 32 + m16;
  const size_t rowA1 = rowA0 + 16;

  for (int half = 0; half < K / 128; ++half) {
    __syncthreads();
    const uint4* gsrc = (const uint4*)(Wsw + half * 32768);
    uint4* ldst = (uint4*)lW;
#pragma unroll
    for (int i = 0; i < 8; ++i) ldst[i * 512 + tid] = gsrc[i * 512 + tid];
    __syncthreads();

#pragma unroll
    for (int kc = 0; kc < 4; ++kc) {
      const int koff = half * 128 + kc * 32 + q * 8;
      const bf16x8 av0 = *(const bf16x8*)(A + rowA0 * K + koff);
      const bf16x8 av1 = *(const bf16x8*)(A + rowA1 * K + koff);
#pragma unroll
      for (int nt = 0; nt < 16; ++nt) {
        const bf16x8 bv = *(const bf16x8*)(&lW[(kc * 16 + nt) * 512 + lane * 8]);
        acc[0][nt] = __builtin_amdgcn_mfma_f32_16x16x32_bf16(av0, bv, acc[0][nt], 0, 0, 0);
        acc[1][nt] = __builtin_amdgcn_mfma_f32_16x16x32_bf16(av1, bv, acc[1][nt], 0, 0, 0);
      }
    }
  }
  const int rq = (lane >> 4) * 4;
#pragma unroll
  for (int t = 0; t < 2; ++t) {
#pragma unroll
    for (int nt = 0; nt < 16; ++nt) {
      const int col = nt * 16 + m16;
      const float bv = bias[col];
#pragma unroll
      for (int r = 0; r < 4; ++r) {
        const size_t row = baseM + wave * 32 + t * 16 + rq + r;
        float v = acc[t][nt][r] + bv;
        v = fmaxf(v, 0.0f);
        out[row * 256 + col] = f2bf(v);
      }
    }
  }
}

// ---------------- readout ----------------
__global__ __launch_bounds__(256) void k_final(const unsigned short* __restrict__ Z,
                                               const float* __restrict__ Wout,
                                               const float* __restrict__ bout,
                                               float* __restrict__ out) {
  const int lane = threadIdx.x & 63;
  const int g = (blockIdx.x * blockDim.x + threadIdx.x) >> 6;  // 0..8191
  const unsigned short* z = Z + (size_t)g * 4096;
  float acc = 0.f;
#pragma unroll
  for (int it = 0; it < 16; ++it) {
    const int idx = (it * 64 + lane) * 4;
    const ushort4 zv = *(const ushort4*)(z + idx);
    const float4 wv = *(const float4*)(Wout + idx);
    acc = fmaf(bf2f(zv.x), wv.x, acc);
    acc = fmaf(bf2f(zv.y), wv.y, acc);
    acc = fmaf(bf2f(zv.z), wv.z, acc);
    acc = fmaf(bf2f(zv.w), wv.w, acc);
  }
#pragma unroll
  for (int off = 32; off > 0; off >>= 1) acc += __shfl_down(acc, off);
  if (lane == 0) out[g] = acc + bout[0];
}

extern "C" void kernel_launch(void* const* d_in, const int* in_sizes, int n_in,
                              void* d_out, int out_size, void* d_ws, size_t ws_size,
                              hipStream_t stream) {
  const float* x    = (const float*)d_in[0];  // [N,128] fp32
  const int*   ei   = (const int*)d_in[1];    // [2,E] int32
  const float* W1   = (const float*)d_in[2];  // [128,256] fp32
  const float* b1   = (const float*)d_in[3];
  const float* W2   = (const float*)d_in[4];  // [256,256] fp32
  const float* b2   = (const float*)d_in[5];
  const float* Wout = (const float*)d_in[6];  // [4096] fp32
  const float* bout = (const float*)d_in[7];
  float* out = (float*)d_out;

  char* ws = (char*)d_ws;
  size_t off = 0;
  auto alloc = [&](size_t bytes) {
    char* p = ws + off;
    off += (bytes + 511) & ~(size_t)511;
    return p;
  };
  int*            row_ptr = (int*)alloc(((size_t)NN + 1) * 4);
  float*          dinv    = (float*)alloc((size_t)NN * 4);
  int*            bktCnt  = (int*)alloc(BKT * 4);
  unsigned int*   bktBuf  = (unsigned int*)alloc((size_t)BKT * BCAP * 4);  // 21 MB
  int*            csr     = (int*)alloc((size_t)NE * 4);
  unsigned short* Wsw1    = (unsigned short*)alloc(128 * 256 * 2);
  unsigned short* Wsw2    = (unsigned short*)alloc(256 * 256 * 2);
  unsigned short* xb      = (unsigned short*)alloc((size_t)NN * 128 * 2);
  unsigned short* bufA    = (unsigned short*)alloc((size_t)NN * 256 * 2);
  unsigned short* bufB    = (unsigned short*)alloc((size_t)NN * 256 * 2);
  (void)in_sizes; (void)n_in; (void)out_size; (void)ws_size;

  const int* src = ei;
  const int* dst = ei + NE;

  hipLaunchKernelGGL(k_bzero,  dim3(1), dim3(256), 0, stream, bktCnt);
  hipLaunchKernelGGL(k_bucket, dim3(NE / 4096), dim3(1024), 0, stream, src, dst, bktCnt, bktBuf);
  hipLaunchKernelGGL(k_csr,    dim3(BKT), dim3(1024), 0, stream, bktCnt, bktBuf, row_ptr, dinv, csr);
  hipLaunchKernelGGL(k_cvt,    dim3(NN * 128 / 4 / 256), dim3(256), 0, stream, x, xb);
  hipLaunchKernelGGL(k_swizzle, dim3(128), dim3(256), 0, stream, W1, Wsw1);
  hipLaunchKernelGGL(k_swizzle, dim3(256), dim3(256), 0, stream, W2, Wsw2);

  // layer 1: two feature-slice passes (gather footprint 16.75 MB each)
  hipLaunchKernelGGL(agg_h<8>, dim3(NN / 4), dim3(256), 0, stream, xb, row_ptr, csr, dinv, bufA, 128, 0);
  hipLaunchKernelGGL(agg_h<8>, dim3(NN / 4), dim3(256), 0, stream, xb, row_ptr, csr, dinv, bufA, 128, 64);
  hipLaunchKernelGGL(k_gemm<128>, dim3(NN / 256), dim3(512), 0, stream, bufA, Wsw1, b1, bufB);
  // layer 2: two feature-slice passes (gather footprint 33.5 MB each)
  hipLaunchKernelGGL(agg_h<16>, dim3(NN / 4), dim3(256), 0, stream, bufB, row_ptr, csr, dinv, bufA, 256, 0);
  hipLaunchKernelGGL(agg_h<16>, dim3(NN / 4), dim3(256), 0, stream, bufB, row_ptr, csr, dinv, bufA, 256, 128);
  hipLaunchKernelGGL(k_gemm<256>, dim3(NN / 256), dim3(512), 0, stream, bufA, Wsw2, b2, bufB);
  // readout
  hipLaunchKernelGGL(k_final, dim3(8192 / 4), dim3(256), 0, stream, bufB, Wout, bout, out);
}